// Round 8
// baseline (643.866 us; speedup 1.0000x reference)
//
#include <hip/hip_runtime.h>
#include <math.h>

#define N_NODES 100000
#define N_EDGES 1600000
#define DIM     128
#define NCLS    64
#define ALPHA   0.1f

#define SCAN_B  98                 // ceil(100000/1024)
#define NF      ((size_t)N_NODES * DIM)
#define STRIPES (N_NODES / 16)     // 6250 exact

typedef __attribute__((ext_vector_type(8))) short  bf16x8;
typedef __attribute__((ext_vector_type(4))) float  f32x4;

// ---- bf16 helpers (storage only; accumulation fp32) ----
__device__ __forceinline__ float bf2f(unsigned short u) {
    return __uint_as_float((unsigned int)u << 16);
}
__device__ __forceinline__ unsigned short f2bf(float x) {
    unsigned int u = __float_as_uint(x);
    u += 0x7FFFu + ((u >> 16) & 1u);          // round-to-nearest-even
    return (unsigned short)(u >> 16);
}

// unpack packed bf16 pair from a u32 without shifts on the high half
#define BFLO(u) __uint_as_float((u) << 16)
#define BFHI(u) __uint_as_float((u) & 0xFFFF0000u)

// ================= direct atomic CSR build =================
// R7: replaces 6-kernel bucketed counting sort (k_part alone was 62 us with
// 3.4x write amplification on ebuf). deg via global atomics, scatter via
// per-node atomic cursors. Within-row edge order is atomic-order
// (non-deterministic) -> only permutes fp32 summation order in SpMM.

__global__ __launch_bounds__(256) void k_deg_direct(const int* __restrict__ dst,
                                                    int* __restrict__ deg) {
    int i = blockIdx.x * 256 + threadIdx.x;
    if (i < N_EDGES) atomicAdd(&deg[dst[i]], 1);
}

__global__ __launch_bounds__(1024) void k_scan1(const int* __restrict__ deg,
                                                int* __restrict__ row_ptr,
                                                int* __restrict__ blocksum) {
    __shared__ int s[1024];
    int t = threadIdx.x;
    int i = blockIdx.x * 1024 + t;
    int v = (i < N_NODES) ? deg[i] : 0;
    s[t] = v;
    __syncthreads();
    for (int off = 1; off < 1024; off <<= 1) {
        int u = (t >= off) ? s[t - off] : 0;
        __syncthreads();
        s[t] += u;
        __syncthreads();
    }
    if (i < N_NODES) row_ptr[i] = s[t] - v;
    if (t == 1023) blocksum[blockIdx.x] = s[1023];
}

__global__ __launch_bounds__(128) void k_scan2(int* __restrict__ blocksum) {
    __shared__ int s[128];
    int t = threadIdx.x;
    int v = (t < SCAN_B) ? blocksum[t] : 0;
    s[t] = v;
    __syncthreads();
    for (int off = 1; off < 128; off <<= 1) {
        int u = (t >= off) ? s[t - off] : 0;
        __syncthreads();
        s[t] += u;
        __syncthreads();
    }
    if (t < SCAN_B) blocksum[t] = s[t] - v;
}

// finalize row_ptr AND re-init the scatter cursor (reuses deg array) so the
// whole build is idempotent per launch (graph-capture safe).
__global__ __launch_bounds__(1024) void k_scan3(int* __restrict__ row_ptr,
                                                const int* __restrict__ blocksum,
                                                int* __restrict__ cursor) {
    int t = threadIdx.x;
    int i = blockIdx.x * 1024 + t;
    if (i < N_NODES) {
        int v = row_ptr[i] + blocksum[blockIdx.x];
        row_ptr[i] = v;
        cursor[i] = v;
    }
    if (i == 0) row_ptr[N_NODES] = N_EDGES;
}

__global__ __launch_bounds__(256) void k_scatter_direct(
    const int* __restrict__ src, const int* __restrict__ dst,
    const float* __restrict__ ew, int* __restrict__ cursor,
    int2* __restrict__ colw) {
    int i = blockIdx.x * 256 + threadIdx.x;
    if (i >= N_EDGES) return;
    int d = dst[i];
    int pos = atomicAdd(&cursor[d], 1);
    colw[pos] = make_int2(src[i], __float_as_int((1.0f - ALPHA) * ew[i]));
}

// ===== weight pack: fp32 -> bf16 B-fragment order =====
// frag idx = ((nt*4 + ch)*64 + lane)*8 + j ;
// value = W[ch*32 + (lane>>4)*8 + j][nt*16 + (lane&15)]
// layers at wp[l*16384] (l=0..3), w_out at wp[65536] (nt 0..3), w_in at wp[73728].
__global__ void k_prepw(const float* __restrict__ gcnw, const float* __restrict__ wout,
                        const float* __restrict__ win, unsigned short* __restrict__ wp) {
    int tid = blockIdx.x * 256 + threadIdx.x;
    if (tid < 65536) {
        int l = tid >> 14;
        int r = tid & 16383;
        int j = r & 7, lane = (r >> 3) & 63, ch = (r >> 9) & 3, nt = r >> 11;
        int n = nt * 16 + (lane & 15);
        int k = ch * 32 + (lane >> 4) * 8 + j;
        wp[tid] = f2bf(gcnw[l * 16384 + k * 128 + n]);
    } else if (tid < 73728) {
        int r = tid - 65536;
        int j = r & 7, lane = (r >> 3) & 63, ch = (r >> 9) & 3, nt = r >> 11; // nt 0..3
        int n = nt * 16 + (lane & 15);
        int k = ch * 32 + (lane >> 4) * 8 + j;
        wp[tid] = f2bf(wout[k * 64 + n]);
    } else if (tid < 90112) {
        int r = tid - 73728;
        int j = r & 7, lane = (r >> 3) & 63, ch = (r >> 9) & 3, nt = r >> 11; // nt 0..7
        int n = nt * 16 + (lane & 15);
        int k = ch * 32 + (lane >> 4) * 8 + j;
        wp[tid] = f2bf(win[k * 128 + n]);
    }
}

// ===== SpMM gather (bf16 rows): hi[i] = ALPHA*h0[i] + sum_e w*h[src] =====
// 16 lanes/row x 4 edge-slots, uint4 loads, 16-edge predicated pipeline.
__global__ __launch_bounds__(256, 8) void k_spmm_csr(
    const int* __restrict__ row_ptr, const int2* __restrict__ colw,
    const unsigned short* __restrict__ h, const unsigned short* __restrict__ h0,
    unsigned short* __restrict__ out) {
    int node = blockIdx.x * 4 + (threadIdx.x >> 6);
    if (node >= N_NODES) return;
    int lane = threadIdx.x & 63;
    int slot = lane >> 4;           // edge slot 0..3
    int seg  = lane & 15;           // 16B segment of the row (8 bf16)
    int beg = row_ptr[node], end = row_ptr[node + 1];

    float acc[8] = {0.f, 0.f, 0.f, 0.f, 0.f, 0.f, 0.f, 0.f};
    if (slot == 0) {                // initial residual added once
        uint4 z = *(const uint4*)(h0 + (size_t)node * DIM + seg * 8);
        acc[0] = ALPHA * BFLO(z.x); acc[1] = ALPHA * BFHI(z.x);
        acc[2] = ALPHA * BFLO(z.y); acc[3] = ALPHA * BFHI(z.y);
        acc[4] = ALPHA * BFLO(z.z); acc[5] = ALPHA * BFHI(z.z);
        acc[6] = ALPHA * BFLO(z.w); acc[7] = ALPHA * BFHI(z.w);
    }

    int last = end - 1;
    for (int e = beg; e < end; e += 16) {
        int e0 = e + slot, e1 = e0 + 4, e2 = e0 + 8, e3 = e0 + 12;
        int2 c0 = colw[min(e0, last)];
        int2 c1 = colw[min(e1, last)];
        int2 c2 = colw[min(e2, last)];
        int2 c3 = colw[min(e3, last)];
        uint4 r0 = *(const uint4*)(h + (size_t)c0.x * DIM + seg * 8);
        uint4 r1 = *(const uint4*)(h + (size_t)c1.x * DIM + seg * 8);
        uint4 r2 = *(const uint4*)(h + (size_t)c2.x * DIM + seg * 8);
        uint4 r3 = *(const uint4*)(h + (size_t)c3.x * DIM + seg * 8);
        float w0 = (e0 < end) ? __int_as_float(c0.y) : 0.f;
        float w1 = (e1 < end) ? __int_as_float(c1.y) : 0.f;
        float w2 = (e2 < end) ? __int_as_float(c2.y) : 0.f;
        float w3 = (e3 < end) ? __int_as_float(c3.y) : 0.f;
        acc[0] += w0 * BFLO(r0.x); acc[1] += w0 * BFHI(r0.x);
        acc[2] += w0 * BFLO(r0.y); acc[3] += w0 * BFHI(r0.y);
        acc[4] += w0 * BFLO(r0.z); acc[5] += w0 * BFHI(r0.z);
        acc[6] += w0 * BFLO(r0.w); acc[7] += w0 * BFHI(r0.w);
        acc[0] += w1 * BFLO(r1.x); acc[1] += w1 * BFHI(r1.x);
        acc[2] += w1 * BFLO(r1.y); acc[3] += w1 * BFHI(r1.y);
        acc[4] += w1 * BFLO(r1.z); acc[5] += w1 * BFHI(r1.z);
        acc[6] += w1 * BFLO(r1.w); acc[7] += w1 * BFHI(r1.w);
        acc[0] += w2 * BFLO(r2.x); acc[1] += w2 * BFHI(r2.x);
        acc[2] += w2 * BFLO(r2.y); acc[3] += w2 * BFHI(r2.y);
        acc[4] += w2 * BFLO(r2.z); acc[5] += w2 * BFHI(r2.z);
        acc[6] += w2 * BFLO(r2.w); acc[7] += w2 * BFHI(r2.w);
        acc[0] += w3 * BFLO(r3.x); acc[1] += w3 * BFHI(r3.x);
        acc[2] += w3 * BFLO(r3.y); acc[3] += w3 * BFHI(r3.y);
        acc[4] += w3 * BFLO(r3.z); acc[5] += w3 * BFHI(r3.z);
        acc[6] += w3 * BFLO(r3.w); acc[7] += w3 * BFHI(r3.w);
    }

    // combine the 4 edge-slots (lanes l, l+16, l+32, l+48 hold same dims)
    #pragma unroll
    for (int j = 0; j < 8; j++) {
        acc[j] += __shfl_xor(acc[j], 16);
        acc[j] += __shfl_xor(acc[j], 32);
    }

    if (slot == 0) {                           // 16 lanes write 16B each
        unsigned int p0 = (unsigned int)f2bf(acc[0]) | ((unsigned int)f2bf(acc[1]) << 16);
        unsigned int p1 = (unsigned int)f2bf(acc[2]) | ((unsigned int)f2bf(acc[3]) << 16);
        unsigned int p2 = (unsigned int)f2bf(acc[4]) | ((unsigned int)f2bf(acc[5]) << 16);
        unsigned int p3 = (unsigned int)f2bf(acc[6]) | ((unsigned int)f2bf(acc[7]) << 16);
        *(uint4*)(out + (size_t)node * DIM + seg * 8) = make_uint4(p0, p1, p2, p3);
    }
}

// ===== MFMA input GEMM: h0 = relu(x @ W_in + b)  (x fp32 -> bf16 in-reg) =====
__global__ __launch_bounds__(256) void k_in_mfma(
    const float* __restrict__ x, const unsigned short* __restrict__ wp,
    const float* __restrict__ b_in, unsigned short* __restrict__ h0) {
    int wave = threadIdx.x >> 6, lane = threadIdx.x & 63;
    int stripe = blockIdx.x * 4 + wave;
    if (stripe >= STRIPES) return;
    int r0 = stripe * 16;
    int m = lane & 15, q = lane >> 4;

    f32x4 acc[8];
    #pragma unroll
    for (int nt = 0; nt < 8; nt++) acc[nt] = (f32x4){0.f, 0.f, 0.f, 0.f};

    const float* xr = x + (size_t)(r0 + m) * DIM + q * 8;
    #pragma unroll
    for (int ch = 0; ch < 4; ch++) {
        float4 a0 = *(const float4*)(xr + ch * 32);
        float4 a1 = *(const float4*)(xr + ch * 32 + 4);
        bf16x8 a;
        a[0] = (short)f2bf(a0.x); a[1] = (short)f2bf(a0.y);
        a[2] = (short)f2bf(a0.z); a[3] = (short)f2bf(a0.w);
        a[4] = (short)f2bf(a1.x); a[5] = (short)f2bf(a1.y);
        a[6] = (short)f2bf(a1.z); a[7] = (short)f2bf(a1.w);
        #pragma unroll
        for (int nt = 0; nt < 8; nt++) {
            bf16x8 b = *(const bf16x8*)(wp + (((nt * 4 + ch) * 64 + lane) << 3));
            acc[nt] = __builtin_amdgcn_mfma_f32_16x16x32_bf16(a, b, acc[nt], 0, 0, 0);
        }
    }

    #pragma unroll
    for (int nt = 0; nt < 8; nt++) {
        int col = nt * 16 + m;
        float bias = b_in[col];
        #pragma unroll
        for (int r = 0; r < 4; r++) {
            int row = r0 + q * 4 + r;
            h0[(size_t)row * DIM + col] = f2bf(fmaxf(acc[nt][r] + bias, 0.f));
        }
    }
}

// ===== MFMA layer GEMM: h = relu(theta*(s@W) + (1-theta)*s + hprev) =====
__global__ __launch_bounds__(256) void k_layer_mfma(
    const unsigned short* __restrict__ s_in, const unsigned short* __restrict__ hprev,
    const unsigned short* __restrict__ wp, unsigned short* __restrict__ hout,
    float theta) {
    int wave = threadIdx.x >> 6, lane = threadIdx.x & 63;
    int stripe = blockIdx.x * 4 + wave;
    if (stripe >= STRIPES) return;
    int r0 = stripe * 16;
    int m = lane & 15, q = lane >> 4;
    float omt = 1.f - theta;

    f32x4 acc[8];
    #pragma unroll
    for (int nt = 0; nt < 8; nt++) acc[nt] = (f32x4){0.f, 0.f, 0.f, 0.f};

    const unsigned short* arow = s_in + (size_t)(r0 + m) * DIM + q * 8;
    #pragma unroll
    for (int ch = 0; ch < 4; ch++) {
        bf16x8 a = *(const bf16x8*)(arow + ch * 32);
        #pragma unroll
        for (int nt = 0; nt < 8; nt++) {
            bf16x8 b = *(const bf16x8*)(wp + (((nt * 4 + ch) * 64 + lane) << 3));
            acc[nt] = __builtin_amdgcn_mfma_f32_16x16x32_bf16(a, b, acc[nt], 0, 0, 0);
        }
    }

    #pragma unroll
    for (int nt = 0; nt < 8; nt++) {
        int col = nt * 16 + m;
        #pragma unroll
        for (int r = 0; r < 4; r++) {
            int row = r0 + q * 4 + r;
            size_t idx = (size_t)row * DIM + col;
            float sup = bf2f(s_in[idx]);
            float hp  = bf2f(hprev[idx]);
            float o = theta * acc[nt][r] + omt * sup + hp;
            hout[idx] = f2bf(fmaxf(o, 0.f));
        }
    }
}

// ===== MFMA output GEMM + log_softmax =====
__global__ __launch_bounds__(256) void k_out_mfma(
    const unsigned short* __restrict__ h, const unsigned short* __restrict__ wp,
    const float* __restrict__ bo, float* __restrict__ out) {
    int wave = threadIdx.x >> 6, lane = threadIdx.x & 63;
    int stripe = blockIdx.x * 4 + wave;
    if (stripe >= STRIPES) return;
    int r0 = stripe * 16;
    int m = lane & 15, q = lane >> 4;

    f32x4 acc[4];
    #pragma unroll
    for (int nt = 0; nt < 4; nt++) acc[nt] = (f32x4){0.f, 0.f, 0.f, 0.f};

    const unsigned short* arow = h + (size_t)(r0 + m) * DIM + q * 8;
    #pragma unroll
    for (int ch = 0; ch < 4; ch++) {
        bf16x8 a = *(const bf16x8*)(arow + ch * 32);
        #pragma unroll
        for (int nt = 0; nt < 4; nt++) {
            bf16x8 b = *(const bf16x8*)(wp + (((nt * 4 + ch) * 64 + lane) << 3));
            acc[nt] = __builtin_amdgcn_mfma_f32_16x16x32_bf16(a, b, acc[nt], 0, 0, 0);
        }
    }

    float v[4][4];
    #pragma unroll
    for (int nt = 0; nt < 4; nt++) {
        float bias = bo[nt * 16 + m];
        #pragma unroll
        for (int r = 0; r < 4; r++) v[nt][r] = acc[nt][r] + bias;
    }
    #pragma unroll
    for (int r = 0; r < 4; r++) {
        float mx = fmaxf(fmaxf(v[0][r], v[1][r]), fmaxf(v[2][r], v[3][r]));
        #pragma unroll
        for (int off = 1; off < 16; off <<= 1) mx = fmaxf(mx, __shfl_xor(mx, off));
        float s = 0.f;
        #pragma unroll
        for (int nt = 0; nt < 4; nt++) s += __expf(v[nt][r] - mx);
        #pragma unroll
        for (int off = 1; off < 16; off <<= 1) s += __shfl_xor(s, off);
        float lse = mx + logf(s);
        int row = r0 + q * 4 + r;
        #pragma unroll
        for (int nt = 0; nt < 4; nt++)
            out[(size_t)row * NCLS + nt * 16 + m] = v[nt][r] - lse;
    }
}

extern "C" void kernel_launch(void* const* d_in, const int* in_sizes, int n_in,
                              void* d_out, int out_size, void* d_ws, size_t ws_size,
                              hipStream_t stream) {
    const float* x    = (const float*)d_in[0];
    const int*   esrc = (const int*)d_in[1];
    const int*   edst = (const int*)d_in[2];
    const float* ew   = (const float*)d_in[3];
    const float* w_in = (const float*)d_in[4];
    const float* b_in = (const float*)d_in[5];
    const float* gcnw = (const float*)d_in[6];   // [4,128,128]
    const float* wout = (const float*)d_in[7];
    const float* bout = (const float*)d_in[8];
    float* out = (float*)d_out;

    // workspace layout
    unsigned short* h0 = (unsigned short*)d_ws;        // NF ushorts each
    unsigned short* hA = h0 + NF;
    unsigned short* hB = hA + NF;
    unsigned short* hi = hB + NF;
    unsigned short* wp = hi + NF;                      // 90112 ushorts packed W
    int2* colw = (int2*)(wp + 90112);                  // E int2 (CSR payload)
    int*  row_ptr  = (int*)(colw + N_EDGES);           // N+1
    int*  deg      = row_ptr + (N_NODES + 1);          // N (degree, then cursor)
    int*  blocksum = deg + N_NODES;                    // SCAN_B

    const int EDGE_B = (N_EDGES + 255) / 256;          // 6250
    const int MFMA_BLOCKS = (STRIPES + 3) / 4;         // 1563

    // ---- weight pack ----
    k_prepw<<<(90112 + 255) / 256, 256, 0, stream>>>(gcnw, wout, w_in, wp);

    // ---- direct atomic CSR build ----
    hipMemsetAsync(deg, 0, N_NODES * sizeof(int), stream);
    k_deg_direct<<<EDGE_B, 256, 0, stream>>>(edst, deg);
    k_scan1<<<SCAN_B, 1024, 0, stream>>>(deg, row_ptr, blocksum);
    k_scan2<<<1, 128, 0, stream>>>(blocksum);
    k_scan3<<<SCAN_B, 1024, 0, stream>>>(row_ptr, blocksum, deg);   // deg -> cursor
    k_scatter_direct<<<EDGE_B, 256, 0, stream>>>(esrc, edst, ew, deg, colw);

    // h0 = relu(x @ w_in + b_in)
    k_in_mfma<<<MFMA_BLOCKS, 256, 0, stream>>>(x, wp + 73728, b_in, h0);

    const unsigned short* hprev = h0;
    unsigned short* bufs[2] = {hA, hB};
    for (int l = 0; l < 4; l++) {
        float theta = logf(0.5f / (float)(l + 2) + 1.0f);
        k_spmm_csr<<<(N_NODES + 3) / 4, 256, 0, stream>>>(row_ptr, colw, hprev, h0, hi);
        unsigned short* hnew = bufs[l & 1];
        k_layer_mfma<<<MFMA_BLOCKS, 256, 0, stream>>>(hi, hprev, wp + (size_t)l * 16384,
                                                      hnew, theta);
        hprev = hnew;
    }

    // out = log_softmax(h @ w_out + b_out)
    k_out_mfma<<<MFMA_BLOCKS, 256, 0, stream>>>(hprev, wp + 65536, bout, out);
}

// Round 9
// 556.384 us; speedup vs baseline: 1.1572x; 1.1572x over previous
//
#include <hip/hip_runtime.h>
#include <math.h>

#define N_NODES 100000
#define N_EDGES 1600000
#define DIM     128
#define NCLS    64
#define ALPHA   0.1f

#define SCAN_B  98                 // ceil(100000/1024)
#define NB      391                // ceil(100000/256) dst-buckets of 256 nodes
#define NF      ((size_t)N_NODES * DIM)
#define STRIPES (N_NODES / 16)     // 6250 exact
#define CHUNK   4096               // R8: 2048->4096, longer per-bucket runs halve write amp

typedef __attribute__((ext_vector_type(8))) short  bf16x8;
typedef __attribute__((ext_vector_type(4))) float  f32x4;
typedef __attribute__((ext_vector_type(2))) float  f32x2;

// ---- bf16 helpers (storage only; accumulation fp32) ----
__device__ __forceinline__ float bf2f(unsigned short u) {
    return __uint_as_float((unsigned int)u << 16);
}
__device__ __forceinline__ unsigned short f2bf(float x) {
    unsigned int u = __float_as_uint(x);
    u += 0x7FFFu + ((u >> 16) & 1u);          // round-to-nearest-even
    return (unsigned short)(u >> 16);
}

// unpack packed bf16 pair from a u32 without shifts on the high half
#define BFLO(u) __uint_as_float((u) << 16)
#define BFHI(u) __uint_as_float((u) & 0xFFFF0000u)

// ================= bucketed CSR build =================
// bucket = dst >> 8 (256 nodes/bucket). ebuf entry: x = src | dst_local<<17, y = 0.9*w.

__global__ __launch_bounds__(256) void k_hist(const int* __restrict__ dst,
                                              int* __restrict__ bucket_cnt) {
    __shared__ int hist[NB];
    int t = threadIdx.x;
    for (int b = t; b < NB; b += 256) hist[b] = 0;
    __syncthreads();
    int base = blockIdx.x * CHUNK;
    int end = min(base + CHUNK, N_EDGES);
    for (int i = base + t; i < end; i += 256)
        atomicAdd(&hist[dst[i] >> 8], 1);
    __syncthreads();
    for (int b = t; b < NB; b += 256)
        if (hist[b]) atomicAdd(&bucket_cnt[b], hist[b]);
}

__global__ __launch_bounds__(512) void k_scanb(const int* __restrict__ bucket_cnt,
                                               int* __restrict__ bucket_base,
                                               int* __restrict__ bucket_cursor) {
    __shared__ int s[512];
    int t = threadIdx.x;
    int v = (t < NB) ? bucket_cnt[t] : 0;
    s[t] = v;
    __syncthreads();
    for (int off = 1; off < 512; off <<= 1) {
        int u = (t >= off) ? s[t - off] : 0;
        __syncthreads();
        s[t] += u;
        __syncthreads();
    }
    if (t < NB) {
        int base = s[t] - v;
        bucket_base[t] = base;
        bucket_cursor[t] = base;
    }
    if (t == 0) bucket_base[NB] = N_EDGES;
}

__global__ __launch_bounds__(256) void k_part(const int* __restrict__ src,
                                              const int* __restrict__ dst,
                                              const float* __restrict__ ew,
                                              int* __restrict__ bucket_cursor,
                                              int2* __restrict__ ebuf) {
    __shared__ int lhist[NB], gbase[NB];
    int t = threadIdx.x;
    for (int b = t; b < NB; b += 256) lhist[b] = 0;
    __syncthreads();
    int base = blockIdx.x * CHUNK;
    int end = min(base + CHUNK, N_EDGES);
    for (int i = base + t; i < end; i += 256)
        atomicAdd(&lhist[dst[i] >> 8], 1);
    __syncthreads();
    for (int b = t; b < NB; b += 256) {
        int c = lhist[b];
        gbase[b] = c ? atomicAdd(&bucket_cursor[b], c) : 0;
        lhist[b] = 0;
    }
    __syncthreads();
    for (int i = base + t; i < end; i += 256) {
        int d = dst[i];
        int b = d >> 8;
        int r = atomicAdd(&lhist[b], 1);
        ebuf[gbase[b] + r] = make_int2(src[i] | ((d & 255) << 17),
                                       __float_as_int((1.0f - ALPHA) * ew[i]));
    }
}

// per-bucket degree via LDS counters (no global atomics)
__global__ __launch_bounds__(256) void k_deg(const int2* __restrict__ ebuf,
                                             const int* __restrict__ bucket_base,
                                             int* __restrict__ deg) {
    __shared__ int cnt[256];
    int t = threadIdx.x, b = blockIdx.x;
    cnt[t] = 0;
    __syncthreads();
    int beg = bucket_base[b], end = bucket_base[b + 1];
    for (int i = beg + t; i < end; i += 256)
        atomicAdd(&cnt[ebuf[i].x >> 17], 1);
    __syncthreads();
    int node = b * 256 + t;
    if (node < N_NODES) deg[node] = cnt[t];
}

__global__ __launch_bounds__(1024) void k_scan1(const int* __restrict__ deg,
                                                int* __restrict__ row_ptr,
                                                int* __restrict__ blocksum) {
    __shared__ int s[1024];
    int t = threadIdx.x;
    int i = blockIdx.x * 1024 + t;
    int v = (i < N_NODES) ? deg[i] : 0;
    s[t] = v;
    __syncthreads();
    for (int off = 1; off < 1024; off <<= 1) {
        int u = (t >= off) ? s[t - off] : 0;
        __syncthreads();
        s[t] += u;
        __syncthreads();
    }
    if (i < N_NODES) row_ptr[i] = s[t] - v;
    if (t == 1023) blocksum[blockIdx.x] = s[1023];
}

__global__ __launch_bounds__(128) void k_scan2(int* __restrict__ blocksum) {
    __shared__ int s[128];
    int t = threadIdx.x;
    int v = (t < SCAN_B) ? blocksum[t] : 0;
    s[t] = v;
    __syncthreads();
    for (int off = 1; off < 128; off <<= 1) {
        int u = (t >= off) ? s[t - off] : 0;
        __syncthreads();
        s[t] += u;
        __syncthreads();
    }
    if (t < SCAN_B) blocksum[t] = s[t] - v;
}

__global__ __launch_bounds__(1024) void k_scan3(int* __restrict__ row_ptr,
                                                const int* __restrict__ blocksum) {
    int t = threadIdx.x;
    int i = blockIdx.x * 1024 + t;
    if (i < N_NODES) row_ptr[i] += blocksum[blockIdx.x];
    if (i == 0) row_ptr[N_NODES] = N_EDGES;
}

// per-bucket counting-sort scatter; LDS cursors, colw writes confined to ~32KB
__global__ __launch_bounds__(256) void k_scatter2(const int2* __restrict__ ebuf,
                                                  const int* __restrict__ bucket_base,
                                                  const int* __restrict__ row_ptr,
                                                  int2* __restrict__ colw) {
    __shared__ int lcur[256];
    int t = threadIdx.x, b = blockIdx.x;
    int node = b * 256 + t;
    lcur[t] = (node < N_NODES) ? row_ptr[node] : 0;
    __syncthreads();
    int beg = bucket_base[b], end = bucket_base[b + 1];
    for (int i = beg + t; i < end; i += 256) {
        int2 e = ebuf[i];
        int pos = atomicAdd(&lcur[e.x >> 17], 1);
        colw[pos] = make_int2(e.x & 0x1FFFF, e.y);
    }
}

// ===== weight pack: fp32 -> bf16 B-fragment order =====
// frag idx = ((nt*4 + ch)*64 + lane)*8 + j ;
// value = W[ch*32 + (lane>>4)*8 + j][nt*16 + (lane&15)]
// layers at wp[l*16384] (l=0..3), w_out at wp[65536] (nt 0..3), w_in at wp[73728].
__global__ void k_prepw(const float* __restrict__ gcnw, const float* __restrict__ wout,
                        const float* __restrict__ win, unsigned short* __restrict__ wp) {
    int tid = blockIdx.x * 256 + threadIdx.x;
    if (tid < 65536) {
        int l = tid >> 14;
        int r = tid & 16383;
        int j = r & 7, lane = (r >> 3) & 63, ch = (r >> 9) & 3, nt = r >> 11;
        int n = nt * 16 + (lane & 15);
        int k = ch * 32 + (lane >> 4) * 8 + j;
        wp[tid] = f2bf(gcnw[l * 16384 + k * 128 + n]);
    } else if (tid < 73728) {
        int r = tid - 65536;
        int j = r & 7, lane = (r >> 3) & 63, ch = (r >> 9) & 3, nt = r >> 11; // nt 0..3
        int n = nt * 16 + (lane & 15);
        int k = ch * 32 + (lane >> 4) * 8 + j;
        wp[tid] = f2bf(wout[k * 64 + n]);
    } else if (tid < 90112) {
        int r = tid - 73728;
        int j = r & 7, lane = (r >> 3) & 63, ch = (r >> 9) & 3, nt = r >> 11; // nt 0..7
        int n = nt * 16 + (lane & 15);
        int k = ch * 32 + (lane >> 4) * 8 + j;
        wp[tid] = f2bf(win[k * 128 + n]);
    }
}

// ===== SpMM gather (bf16 rows): hi[i] = ALPHA*h0[i] + sum_e w*h[src] =====
// 16 lanes/row x 4 edge-slots, uint4 loads, 16-edge predicated pipeline.
// R8: f32x2 accumulators to induce v_pk_fma_f32 (packed f32, full-rate CDNA).
#define ACC4(rr, ww) {                                        \
    f32x2 t;                                                  \
    t.x = BFLO(rr.x); t.y = BFHI(rr.x); acc2[0] += ww * t;    \
    t.x = BFLO(rr.y); t.y = BFHI(rr.y); acc2[1] += ww * t;    \
    t.x = BFLO(rr.z); t.y = BFHI(rr.z); acc2[2] += ww * t;    \
    t.x = BFLO(rr.w); t.y = BFHI(rr.w); acc2[3] += ww * t; }

__global__ __launch_bounds__(256, 8) void k_spmm_csr(
    const int* __restrict__ row_ptr, const int2* __restrict__ colw,
    const unsigned short* __restrict__ h, const unsigned short* __restrict__ h0,
    unsigned short* __restrict__ out) {
    int node = blockIdx.x * 4 + (threadIdx.x >> 6);
    if (node >= N_NODES) return;
    int lane = threadIdx.x & 63;
    int slot = lane >> 4;           // edge slot 0..3
    int seg  = lane & 15;           // 16B segment of the row (8 bf16)
    int beg = row_ptr[node], end = row_ptr[node + 1];

    f32x2 acc2[4];
    #pragma unroll
    for (int j = 0; j < 4; j++) acc2[j] = (f32x2){0.f, 0.f};
    if (slot == 0) {                // initial residual added once
        uint4 z = *(const uint4*)(h0 + (size_t)node * DIM + seg * 8);
        acc2[0].x = ALPHA * BFLO(z.x); acc2[0].y = ALPHA * BFHI(z.x);
        acc2[1].x = ALPHA * BFLO(z.y); acc2[1].y = ALPHA * BFHI(z.y);
        acc2[2].x = ALPHA * BFLO(z.z); acc2[2].y = ALPHA * BFHI(z.z);
        acc2[3].x = ALPHA * BFLO(z.w); acc2[3].y = ALPHA * BFHI(z.w);
    }

    int last = end - 1;
    for (int e = beg; e < end; e += 16) {
        int e0 = e + slot, e1 = e0 + 4, e2 = e0 + 8, e3 = e0 + 12;
        int2 c0 = colw[min(e0, last)];
        int2 c1 = colw[min(e1, last)];
        int2 c2 = colw[min(e2, last)];
        int2 c3 = colw[min(e3, last)];
        uint4 r0 = *(const uint4*)(h + (size_t)c0.x * DIM + seg * 8);
        uint4 r1 = *(const uint4*)(h + (size_t)c1.x * DIM + seg * 8);
        uint4 r2 = *(const uint4*)(h + (size_t)c2.x * DIM + seg * 8);
        uint4 r3 = *(const uint4*)(h + (size_t)c3.x * DIM + seg * 8);
        float w0 = (e0 < end) ? __int_as_float(c0.y) : 0.f;
        float w1 = (e1 < end) ? __int_as_float(c1.y) : 0.f;
        float w2 = (e2 < end) ? __int_as_float(c2.y) : 0.f;
        float w3 = (e3 < end) ? __int_as_float(c3.y) : 0.f;
        ACC4(r0, w0);
        ACC4(r1, w1);
        ACC4(r2, w2);
        ACC4(r3, w3);
    }

    // combine the 4 edge-slots (lanes l, l+16, l+32, l+48 hold same dims)
    #pragma unroll
    for (int j = 0; j < 4; j++) {
        acc2[j].x += __shfl_xor(acc2[j].x, 16);
        acc2[j].y += __shfl_xor(acc2[j].y, 16);
        acc2[j].x += __shfl_xor(acc2[j].x, 32);
        acc2[j].y += __shfl_xor(acc2[j].y, 32);
    }

    if (slot == 0) {                           // 16 lanes write 16B each
        unsigned int p0 = (unsigned int)f2bf(acc2[0].x) | ((unsigned int)f2bf(acc2[0].y) << 16);
        unsigned int p1 = (unsigned int)f2bf(acc2[1].x) | ((unsigned int)f2bf(acc2[1].y) << 16);
        unsigned int p2 = (unsigned int)f2bf(acc2[2].x) | ((unsigned int)f2bf(acc2[2].y) << 16);
        unsigned int p3 = (unsigned int)f2bf(acc2[3].x) | ((unsigned int)f2bf(acc2[3].y) << 16);
        *(uint4*)(out + (size_t)node * DIM + seg * 8) = make_uint4(p0, p1, p2, p3);
    }
}

// ===== MFMA input GEMM: h0 = relu(x @ W_in + b)  (x fp32 -> bf16 in-reg) =====
__global__ __launch_bounds__(256) void k_in_mfma(
    const float* __restrict__ x, const unsigned short* __restrict__ wp,
    const float* __restrict__ b_in, unsigned short* __restrict__ h0) {
    int wave = threadIdx.x >> 6, lane = threadIdx.x & 63;
    int stripe = blockIdx.x * 4 + wave;
    if (stripe >= STRIPES) return;
    int r0 = stripe * 16;
    int m = lane & 15, q = lane >> 4;

    f32x4 acc[8];
    #pragma unroll
    for (int nt = 0; nt < 8; nt++) acc[nt] = (f32x4){0.f, 0.f, 0.f, 0.f};

    const float* xr = x + (size_t)(r0 + m) * DIM + q * 8;
    #pragma unroll
    for (int ch = 0; ch < 4; ch++) {
        float4 a0 = *(const float4*)(xr + ch * 32);
        float4 a1 = *(const float4*)(xr + ch * 32 + 4);
        bf16x8 a;
        a[0] = (short)f2bf(a0.x); a[1] = (short)f2bf(a0.y);
        a[2] = (short)f2bf(a0.z); a[3] = (short)f2bf(a0.w);
        a[4] = (short)f2bf(a1.x); a[5] = (short)f2bf(a1.y);
        a[6] = (short)f2bf(a1.z); a[7] = (short)f2bf(a1.w);
        #pragma unroll
        for (int nt = 0; nt < 8; nt++) {
            bf16x8 b = *(const bf16x8*)(wp + (((nt * 4 + ch) * 64 + lane) << 3));
            acc[nt] = __builtin_amdgcn_mfma_f32_16x16x32_bf16(a, b, acc[nt], 0, 0, 0);
        }
    }

    #pragma unroll
    for (int nt = 0; nt < 8; nt++) {
        int col = nt * 16 + m;
        float bias = b_in[col];
        #pragma unroll
        for (int r = 0; r < 4; r++) {
            int row = r0 + q * 4 + r;
            h0[(size_t)row * DIM + col] = f2bf(fmaxf(acc[nt][r] + bias, 0.f));
        }
    }
}

// ===== MFMA layer GEMM: h = relu(theta*(s@W) + (1-theta)*s + hprev) =====
__global__ __launch_bounds__(256) void k_layer_mfma(
    const unsigned short* __restrict__ s_in, const unsigned short* __restrict__ hprev,
    const unsigned short* __restrict__ wp, unsigned short* __restrict__ hout,
    float theta) {
    int wave = threadIdx.x >> 6, lane = threadIdx.x & 63;
    int stripe = blockIdx.x * 4 + wave;
    if (stripe >= STRIPES) return;
    int r0 = stripe * 16;
    int m = lane & 15, q = lane >> 4;
    float omt = 1.f - theta;

    f32x4 acc[8];
    #pragma unroll
    for (int nt = 0; nt < 8; nt++) acc[nt] = (f32x4){0.f, 0.f, 0.f, 0.f};

    const unsigned short* arow = s_in + (size_t)(r0 + m) * DIM + q * 8;
    #pragma unroll
    for (int ch = 0; ch < 4; ch++) {
        bf16x8 a = *(const bf16x8*)(arow + ch * 32);
        #pragma unroll
        for (int nt = 0; nt < 8; nt++) {
            bf16x8 b = *(const bf16x8*)(wp + (((nt * 4 + ch) * 64 + lane) << 3));
            acc[nt] = __builtin_amdgcn_mfma_f32_16x16x32_bf16(a, b, acc[nt], 0, 0, 0);
        }
    }

    #pragma unroll
    for (int nt = 0; nt < 8; nt++) {
        int col = nt * 16 + m;
        #pragma unroll
        for (int r = 0; r < 4; r++) {
            int row = r0 + q * 4 + r;
            size_t idx = (size_t)row * DIM + col;
            float sup = bf2f(s_in[idx]);
            float hp  = bf2f(hprev[idx]);
            float o = theta * acc[nt][r] + omt * sup + hp;
            hout[idx] = f2bf(fmaxf(o, 0.f));
        }
    }
}

// ===== MFMA output GEMM + log_softmax =====
__global__ __launch_bounds__(256) void k_out_mfma(
    const unsigned short* __restrict__ h, const unsigned short* __restrict__ wp,
    const float* __restrict__ bo, float* __restrict__ out) {
    int wave = threadIdx.x >> 6, lane = threadIdx.x & 63;
    int stripe = blockIdx.x * 4 + wave;
    if (stripe >= STRIPES) return;
    int r0 = stripe * 16;
    int m = lane & 15, q = lane >> 4;

    f32x4 acc[4];
    #pragma unroll
    for (int nt = 0; nt < 4; nt++) acc[nt] = (f32x4){0.f, 0.f, 0.f, 0.f};

    const unsigned short* arow = h + (size_t)(r0 + m) * DIM + q * 8;
    #pragma unroll
    for (int ch = 0; ch < 4; ch++) {
        bf16x8 a = *(const bf16x8*)(arow + ch * 32);
        #pragma unroll
        for (int nt = 0; nt < 4; nt++) {
            bf16x8 b = *(const bf16x8*)(wp + (((nt * 4 + ch) * 64 + lane) << 3));
            acc[nt] = __builtin_amdgcn_mfma_f32_16x16x32_bf16(a, b, acc[nt], 0, 0, 0);
        }
    }

    float v[4][4];
    #pragma unroll
    for (int nt = 0; nt < 4; nt++) {
        float bias = bo[nt * 16 + m];
        #pragma unroll
        for (int r = 0; r < 4; r++) v[nt][r] = acc[nt][r] + bias;
    }
    #pragma unroll
    for (int r = 0; r < 4; r++) {
        float mx = fmaxf(fmaxf(v[0][r], v[1][r]), fmaxf(v[2][r], v[3][r]));
        #pragma unroll
        for (int off = 1; off < 16; off <<= 1) mx = fmaxf(mx, __shfl_xor(mx, off));
        float s = 0.f;
        #pragma unroll
        for (int nt = 0; nt < 4; nt++) s += __expf(v[nt][r] - mx);
        #pragma unroll
        for (int off = 1; off < 16; off <<= 1) s += __shfl_xor(s, off);
        float lse = mx + logf(s);
        int row = r0 + q * 4 + r;
        #pragma unroll
        for (int nt = 0; nt < 4; nt++)
            out[(size_t)row * NCLS + nt * 16 + m] = v[nt][r] - lse;
    }
}

extern "C" void kernel_launch(void* const* d_in, const int* in_sizes, int n_in,
                              void* d_out, int out_size, void* d_ws, size_t ws_size,
                              hipStream_t stream) {
    const float* x    = (const float*)d_in[0];
    const int*   esrc = (const int*)d_in[1];
    const int*   edst = (const int*)d_in[2];
    const float* ew   = (const float*)d_in[3];
    const float* w_in = (const float*)d_in[4];
    const float* b_in = (const float*)d_in[5];
    const float* gcnw = (const float*)d_in[6];   // [4,128,128]
    const float* wout = (const float*)d_in[7];
    const float* bout = (const float*)d_in[8];
    float* out = (float*)d_out;

    // workspace layout
    unsigned short* h0 = (unsigned short*)d_ws;        // NF ushorts each
    unsigned short* hA = h0 + NF;
    unsigned short* hB = hA + NF;
    unsigned short* hi = hB + NF;
    unsigned short* wp = hi + NF;                      // 90112 ushorts packed W
    int2* colw = (int2*)(wp + 90112);                  // E int2
    int2* ebuf = colw + N_EDGES;                       // E int2 (bucket-grouped)
    int*  row_ptr       = (int*)(ebuf + N_EDGES);      // N+1
    int*  deg           = row_ptr + (N_NODES + 1);     // N
    int*  blocksum      = deg + N_NODES;               // SCAN_B
    int*  bucket_cnt    = blocksum + SCAN_B;           // NB
    int*  bucket_base   = bucket_cnt + NB;             // NB+1
    int*  bucket_cursor = bucket_base + (NB + 1);      // NB

    const int PART_B = (N_EDGES + CHUNK - 1) / CHUNK;  // 391
    const int MFMA_BLOCKS = (STRIPES + 3) / 4;

    // ---- weight pack ----
    k_prepw<<<(90112 + 255) / 256, 256, 0, stream>>>(gcnw, wout, w_in, wp);

    // ---- bucketed CSR build ----
    hipMemsetAsync(bucket_cnt, 0, NB * sizeof(int), stream);
    k_hist<<<PART_B, 256, 0, stream>>>(edst, bucket_cnt);
    k_scanb<<<1, 512, 0, stream>>>(bucket_cnt, bucket_base, bucket_cursor);
    k_part<<<PART_B, 256, 0, stream>>>(esrc, edst, ew, bucket_cursor, ebuf);
    k_deg<<<NB, 256, 0, stream>>>(ebuf, bucket_base, deg);
    k_scan1<<<SCAN_B, 1024, 0, stream>>>(deg, row_ptr, blocksum);
    k_scan2<<<1, 128, 0, stream>>>(blocksum);
    k_scan3<<<SCAN_B, 1024, 0, stream>>>(row_ptr, blocksum);
    k_scatter2<<<NB, 256, 0, stream>>>(ebuf, bucket_base, row_ptr, colw);

    // h0 = relu(x @ w_in + b_in)
    k_in_mfma<<<MFMA_BLOCKS, 256, 0, stream>>>(x, wp + 73728, b_in, h0);

    const unsigned short* hprev = h0;
    unsigned short* bufs[2] = {hA, hB};
    for (int l = 0; l < 4; l++) {
        float theta = logf(0.5f / (float)(l + 2) + 1.0f);
        k_spmm_csr<<<(N_NODES + 3) / 4, 256, 0, stream>>>(row_ptr, colw, hprev, h0, hi);
        unsigned short* hnew = bufs[l & 1];
        k_layer_mfma<<<MFMA_BLOCKS, 256, 0, stream>>>(hi, hprev, wp + (size_t)l * 16384,
                                                      hnew, theta);
        hprev = hnew;
    }

    // out = log_softmax(h @ w_out + b_out)
    k_out_mfma<<<MFMA_BLOCKS, 256, 0, stream>>>(hprev, wp + 65536, bout, out);
}

// Round 11
// 551.711 us; speedup vs baseline: 1.1670x; 1.0085x over previous
//
#include <hip/hip_runtime.h>
#include <hip/hip_fp16.h>
#include <math.h>

#define N_NODES 100000
#define N_EDGES 1600000
#define DIM     128
#define NCLS    64
#define ALPHA   0.1f

#define SCAN_B  98                 // ceil(100000/1024)
#define NB      391                // ceil(100000/256) dst-buckets of 256 nodes
#define NF      ((size_t)N_NODES * DIM)
#define STRIPES (N_NODES / 16)     // 6250 exact
#define CHUNK   4096               // R8: longer per-bucket runs halve write amp

typedef __attribute__((ext_vector_type(8))) _Float16 f16x8;
typedef __attribute__((ext_vector_type(4))) float    f32x4;

// ---- fp16 pair bitcast helpers ----
__device__ __forceinline__ __half2 u2h2(unsigned int u) {
    union { unsigned int u; __half2 h; } x; x.u = u; return x.h;
}
__device__ __forceinline__ unsigned int h22u(__half2 h) {
    union { unsigned int u; __half2 h; } x; x.h = h; return x.u;
}

// ================= bucketed CSR build =================
// bucket = dst >> 8 (256 nodes/bucket). ebuf entry: x = src | dst_local<<17, y = 0.9*w (f32).

__global__ __launch_bounds__(256) void k_hist(const int* __restrict__ dst,
                                              int* __restrict__ bucket_cnt) {
    __shared__ int hist[NB];
    int t = threadIdx.x;
    for (int b = t; b < NB; b += 256) hist[b] = 0;
    __syncthreads();
    int base = blockIdx.x * CHUNK;
    int end = min(base + CHUNK, N_EDGES);
    for (int i = base + t; i < end; i += 256)
        atomicAdd(&hist[dst[i] >> 8], 1);
    __syncthreads();
    for (int b = t; b < NB; b += 256)
        if (hist[b]) atomicAdd(&bucket_cnt[b], hist[b]);
}

__global__ __launch_bounds__(512) void k_scanb(const int* __restrict__ bucket_cnt,
                                               int* __restrict__ bucket_base,
                                               int* __restrict__ bucket_cursor) {
    __shared__ int s[512];
    int t = threadIdx.x;
    int v = (t < NB) ? bucket_cnt[t] : 0;
    s[t] = v;
    __syncthreads();
    for (int off = 1; off < 512; off <<= 1) {
        int u = (t >= off) ? s[t - off] : 0;
        __syncthreads();
        s[t] += u;
        __syncthreads();
    }
    if (t < NB) {
        int base = s[t] - v;
        bucket_base[t] = base;
        bucket_cursor[t] = base;
    }
    if (t == 0) bucket_base[NB] = N_EDGES;
}

__global__ __launch_bounds__(256) void k_part(const int* __restrict__ src,
                                              const int* __restrict__ dst,
                                              const float* __restrict__ ew,
                                              int* __restrict__ bucket_cursor,
                                              int2* __restrict__ ebuf) {
    __shared__ int lhist[NB], gbase[NB];
    int t = threadIdx.x;
    for (int b = t; b < NB; b += 256) lhist[b] = 0;
    __syncthreads();
    int base = blockIdx.x * CHUNK;
    int end = min(base + CHUNK, N_EDGES);
    for (int i = base + t; i < end; i += 256)
        atomicAdd(&lhist[dst[i] >> 8], 1);
    __syncthreads();
    for (int b = t; b < NB; b += 256) {
        int c = lhist[b];
        gbase[b] = c ? atomicAdd(&bucket_cursor[b], c) : 0;
        lhist[b] = 0;
    }
    __syncthreads();
    for (int i = base + t; i < end; i += 256) {
        int d = dst[i];
        int b = d >> 8;
        int r = atomicAdd(&lhist[b], 1);
        ebuf[gbase[b] + r] = make_int2(src[i] | ((d & 255) << 17),
                                       __float_as_int((1.0f - ALPHA) * ew[i]));
    }
}

// per-bucket degree via LDS counters (no global atomics)
__global__ __launch_bounds__(256) void k_deg(const int2* __restrict__ ebuf,
                                             const int* __restrict__ bucket_base,
                                             int* __restrict__ deg) {
    __shared__ int cnt[256];
    int t = threadIdx.x, b = blockIdx.x;
    cnt[t] = 0;
    __syncthreads();
    int beg = bucket_base[b], end = bucket_base[b + 1];
    for (int i = beg + t; i < end; i += 256)
        atomicAdd(&cnt[ebuf[i].x >> 17], 1);
    __syncthreads();
    int node = b * 256 + t;
    if (node < N_NODES) deg[node] = cnt[t];
}

__global__ __launch_bounds__(1024) void k_scan1(const int* __restrict__ deg,
                                                int* __restrict__ row_ptr,
                                                int* __restrict__ blocksum) {
    __shared__ int s[1024];
    int t = threadIdx.x;
    int i = blockIdx.x * 1024 + t;
    int v = (i < N_NODES) ? deg[i] : 0;
    s[t] = v;
    __syncthreads();
    for (int off = 1; off < 1024; off <<= 1) {
        int u = (t >= off) ? s[t - off] : 0;
        __syncthreads();
        s[t] += u;
        __syncthreads();
    }
    if (i < N_NODES) row_ptr[i] = s[t] - v;
    if (t == 1023) blocksum[blockIdx.x] = s[1023];
}

__global__ __launch_bounds__(128) void k_scan2(int* __restrict__ blocksum) {
    __shared__ int s[128];
    int t = threadIdx.x;
    int v = (t < SCAN_B) ? blocksum[t] : 0;
    s[t] = v;
    __syncthreads();
    for (int off = 1; off < 128; off <<= 1) {
        int u = (t >= off) ? s[t - off] : 0;
        __syncthreads();
        s[t] += u;
        __syncthreads();
    }
    if (t < SCAN_B) blocksum[t] = s[t] - v;
}

__global__ __launch_bounds__(1024) void k_scan3(int* __restrict__ row_ptr,
                                                const int* __restrict__ blocksum) {
    int t = threadIdx.x;
    int i = blockIdx.x * 1024 + t;
    if (i < N_NODES) row_ptr[i] += blocksum[blockIdx.x];
    if (i == 0) row_ptr[N_NODES] = N_EDGES;
}

// per-bucket counting-sort scatter; LDS cursors, colw writes confined to ~32KB
// R9: colw.y now stores the edge weight pre-packed as half2(w,w).
__global__ __launch_bounds__(256) void k_scatter2(const int2* __restrict__ ebuf,
                                                  const int* __restrict__ bucket_base,
                                                  const int* __restrict__ row_ptr,
                                                  int2* __restrict__ colw) {
    __shared__ int lcur[256];
    int t = threadIdx.x, b = blockIdx.x;
    int node = b * 256 + t;
    lcur[t] = (node < N_NODES) ? row_ptr[node] : 0;
    __syncthreads();
    int beg = bucket_base[b], end = bucket_base[b + 1];
    for (int i = beg + t; i < end; i += 256) {
        int2 e = ebuf[i];
        int pos = atomicAdd(&lcur[e.x >> 17], 1);
        unsigned int w2 = h22u(__float2half2_rn(__int_as_float(e.y)));
        colw[pos] = make_int2(e.x & 0x1FFFF, (int)w2);
    }
}

// ===== weight pack: fp32 -> fp16 B-fragment order =====
// frag idx = ((nt*4 + ch)*64 + lane)*8 + j ;
// value = W[ch*32 + (lane>>4)*8 + j][nt*16 + (lane&15)]
// layers at wp[l*16384] (l=0..3), w_out at wp[65536] (nt 0..3), w_in at wp[73728].
__global__ void k_prepw(const float* __restrict__ gcnw, const float* __restrict__ wout,
                        const float* __restrict__ win, unsigned short* __restrict__ wp) {
    int tid = blockIdx.x * 256 + threadIdx.x;
    if (tid < 65536) {
        int l = tid >> 14;
        int r = tid & 16383;
        int j = r & 7, lane = (r >> 3) & 63, ch = (r >> 9) & 3, nt = r >> 11;
        int n = nt * 16 + (lane & 15);
        int k = ch * 32 + (lane >> 4) * 8 + j;
        wp[tid] = __half_as_ushort(__float2half(gcnw[l * 16384 + k * 128 + n]));
    } else if (tid < 73728) {
        int r = tid - 65536;
        int j = r & 7, lane = (r >> 3) & 63, ch = (r >> 9) & 3, nt = r >> 11; // nt 0..3
        int n = nt * 16 + (lane & 15);
        int k = ch * 32 + (lane >> 4) * 8 + j;
        wp[tid] = __half_as_ushort(__float2half(wout[k * 64 + n]));
    } else if (tid < 90112) {
        int r = tid - 73728;
        int j = r & 7, lane = (r >> 3) & 63, ch = (r >> 9) & 3, nt = r >> 11; // nt 0..7
        int n = nt * 16 + (lane & 15);
        int k = ch * 32 + (lane >> 4) * 8 + j;
        wp[tid] = __half_as_ushort(__float2half(win[k * 128 + n]));
    }
}

// ===== SpMM gather (fp16 rows): hi[i] = ALPHA*h0[i] + sum_e w*h[src] =====
// 16 lanes/row x 4 edge-slots, uint4 loads, 16-edge predicated pipeline.
// R9: fp16 storage + __hfma2 (v_pk_fma_f16) accumulation — 4 VALU per 16B
// instead of 12 (bf16 unpack+fma). Weights pre-packed half2 in colw.y.
__global__ __launch_bounds__(256, 8) void k_spmm_csr(
    const int* __restrict__ row_ptr, const int2* __restrict__ colw,
    const unsigned short* __restrict__ h, const unsigned short* __restrict__ h0,
    unsigned short* __restrict__ out) {
    int node = blockIdx.x * 4 + (threadIdx.x >> 6);
    if (node >= N_NODES) return;
    int lane = threadIdx.x & 63;
    int slot = lane >> 4;           // edge slot 0..3
    int seg  = lane & 15;           // 16B segment of the row (8 fp16)
    int beg = row_ptr[node], end = row_ptr[node + 1];

    __half2 z2 = __float2half2_rn(0.f);
    __half2 acc2[4] = {z2, z2, z2, z2};
    if (slot == 0) {                // initial residual added once
        uint4 z = *(const uint4*)(h0 + (size_t)node * DIM + seg * 8);
        __half2 al2 = __float2half2_rn(ALPHA);
        acc2[0] = __hmul2(al2, u2h2(z.x));
        acc2[1] = __hmul2(al2, u2h2(z.y));
        acc2[2] = __hmul2(al2, u2h2(z.z));
        acc2[3] = __hmul2(al2, u2h2(z.w));
    }

    int last = end - 1;
    for (int e = beg; e < end; e += 16) {
        int e0 = e + slot, e1 = e0 + 4, e2 = e0 + 8, e3 = e0 + 12;
        int2 c0 = colw[min(e0, last)];
        int2 c1 = colw[min(e1, last)];
        int2 c2 = colw[min(e2, last)];
        int2 c3 = colw[min(e3, last)];
        uint4 r0 = *(const uint4*)(h + (size_t)c0.x * DIM + seg * 8);
        uint4 r1 = *(const uint4*)(h + (size_t)c1.x * DIM + seg * 8);
        uint4 r2 = *(const uint4*)(h + (size_t)c2.x * DIM + seg * 8);
        uint4 r3 = *(const uint4*)(h + (size_t)c3.x * DIM + seg * 8);
        __half2 w0 = (e0 < end) ? u2h2((unsigned int)c0.y) : z2;
        __half2 w1 = (e1 < end) ? u2h2((unsigned int)c1.y) : z2;
        __half2 w2 = (e2 < end) ? u2h2((unsigned int)c2.y) : z2;
        __half2 w3 = (e3 < end) ? u2h2((unsigned int)c3.y) : z2;
        acc2[0] = __hfma2(w0, u2h2(r0.x), acc2[0]);
        acc2[1] = __hfma2(w0, u2h2(r0.y), acc2[1]);
        acc2[2] = __hfma2(w0, u2h2(r0.z), acc2[2]);
        acc2[3] = __hfma2(w0, u2h2(r0.w), acc2[3]);
        acc2[0] = __hfma2(w1, u2h2(r1.x), acc2[0]);
        acc2[1] = __hfma2(w1, u2h2(r1.y), acc2[1]);
        acc2[2] = __hfma2(w1, u2h2(r1.z), acc2[2]);
        acc2[3] = __hfma2(w1, u2h2(r1.w), acc2[3]);
        acc2[0] = __hfma2(w2, u2h2(r2.x), acc2[0]);
        acc2[1] = __hfma2(w2, u2h2(r2.y), acc2[1]);
        acc2[2] = __hfma2(w2, u2h2(r2.z), acc2[2]);
        acc2[3] = __hfma2(w2, u2h2(r2.w), acc2[3]);
        acc2[0] = __hfma2(w3, u2h2(r3.x), acc2[0]);
        acc2[1] = __hfma2(w3, u2h2(r3.y), acc2[1]);
        acc2[2] = __hfma2(w3, u2h2(r3.z), acc2[2]);
        acc2[3] = __hfma2(w3, u2h2(r3.w), acc2[3]);
    }

    // combine the 4 edge-slots (lanes l, l+16, l+32, l+48 hold same dims)
    #pragma unroll
    for (int j = 0; j < 4; j++) {
        unsigned int u = __shfl_xor(h22u(acc2[j]), 16);
        acc2[j] = __hadd2(acc2[j], u2h2(u));
        u = __shfl_xor(h22u(acc2[j]), 32);
        acc2[j] = __hadd2(acc2[j], u2h2(u));
    }

    if (slot == 0) {                           // 16 lanes write 16B each
        *(uint4*)(out + (size_t)node * DIM + seg * 8) =
            make_uint4(h22u(acc2[0]), h22u(acc2[1]), h22u(acc2[2]), h22u(acc2[3]));
    }
}

// ===== MFMA input GEMM: h0 = relu(x @ W_in + b)  (x fp32 -> fp16 in-reg) =====
__global__ __launch_bounds__(256) void k_in_mfma(
    const float* __restrict__ x, const unsigned short* __restrict__ wp,
    const float* __restrict__ b_in, unsigned short* __restrict__ h0) {
    int wave = threadIdx.x >> 6, lane = threadIdx.x & 63;
    int stripe = blockIdx.x * 4 + wave;
    if (stripe >= STRIPES) return;
    int r0 = stripe * 16;
    int m = lane & 15, q = lane >> 4;

    f32x4 acc[8];
    #pragma unroll
    for (int nt = 0; nt < 8; nt++) acc[nt] = (f32x4){0.f, 0.f, 0.f, 0.f};

    const float* xr = x + (size_t)(r0 + m) * DIM + q * 8;
    #pragma unroll
    for (int ch = 0; ch < 4; ch++) {
        float4 a0 = *(const float4*)(xr + ch * 32);
        float4 a1 = *(const float4*)(xr + ch * 32 + 4);
        f16x8 a;
        a[0] = (_Float16)a0.x; a[1] = (_Float16)a0.y;
        a[2] = (_Float16)a0.z; a[3] = (_Float16)a0.w;
        a[4] = (_Float16)a1.x; a[5] = (_Float16)a1.y;
        a[6] = (_Float16)a1.z; a[7] = (_Float16)a1.w;
        #pragma unroll
        for (int nt = 0; nt < 8; nt++) {
            f16x8 b = *(const f16x8*)(wp + (((nt * 4 + ch) * 64 + lane) << 3));
            acc[nt] = __builtin_amdgcn_mfma_f32_16x16x32_f16(a, b, acc[nt], 0, 0, 0);
        }
    }

    #pragma unroll
    for (int nt = 0; nt < 8; nt++) {
        int col = nt * 16 + m;
        float bias = b_in[col];
        #pragma unroll
        for (int r = 0; r < 4; r++) {
            int row = r0 + q * 4 + r;
            h0[(size_t)row * DIM + col] =
                __half_as_ushort(__float2half(fmaxf(acc[nt][r] + bias, 0.f)));
        }
    }
}

// ===== MFMA layer GEMM: h = relu(theta*(s@W) + (1-theta)*s + hprev) =====
__global__ __launch_bounds__(256) void k_layer_mfma(
    const unsigned short* __restrict__ s_in, const unsigned short* __restrict__ hprev,
    const unsigned short* __restrict__ wp, unsigned short* __restrict__ hout,
    float theta) {
    int wave = threadIdx.x >> 6, lane = threadIdx.x & 63;
    int stripe = blockIdx.x * 4 + wave;
    if (stripe >= STRIPES) return;
    int r0 = stripe * 16;
    int m = lane & 15, q = lane >> 4;
    float omt = 1.f - theta;

    f32x4 acc[8];
    #pragma unroll
    for (int nt = 0; nt < 8; nt++) acc[nt] = (f32x4){0.f, 0.f, 0.f, 0.f};

    const unsigned short* arow = s_in + (size_t)(r0 + m) * DIM + q * 8;
    #pragma unroll
    for (int ch = 0; ch < 4; ch++) {
        f16x8 a = *(const f16x8*)(arow + ch * 32);
        #pragma unroll
        for (int nt = 0; nt < 8; nt++) {
            f16x8 b = *(const f16x8*)(wp + (((nt * 4 + ch) * 64 + lane) << 3));
            acc[nt] = __builtin_amdgcn_mfma_f32_16x16x32_f16(a, b, acc[nt], 0, 0, 0);
        }
    }

    #pragma unroll
    for (int nt = 0; nt < 8; nt++) {
        int col = nt * 16 + m;
        #pragma unroll
        for (int r = 0; r < 4; r++) {
            int row = r0 + q * 4 + r;
            size_t idx = (size_t)row * DIM + col;
            float sup = __half2float(__ushort_as_half(s_in[idx]));
            float hp  = __half2float(__ushort_as_half(hprev[idx]));
            float o = theta * acc[nt][r] + omt * sup + hp;
            hout[idx] = __half_as_ushort(__float2half(fmaxf(o, 0.f)));
        }
    }
}

// ===== MFMA output GEMM + log_softmax =====
__global__ __launch_bounds__(256) void k_out_mfma(
    const unsigned short* __restrict__ h, const unsigned short* __restrict__ wp,
    const float* __restrict__ bo, float* __restrict__ out) {
    int wave = threadIdx.x >> 6, lane = threadIdx.x & 63;
    int stripe = blockIdx.x * 4 + wave;
    if (stripe >= STRIPES) return;
    int r0 = stripe * 16;
    int m = lane & 15, q = lane >> 4;

    f32x4 acc[4];
    #pragma unroll
    for (int nt = 0; nt < 4; nt++) acc[nt] = (f32x4){0.f, 0.f, 0.f, 0.f};

    const unsigned short* arow = h + (size_t)(r0 + m) * DIM + q * 8;
    #pragma unroll
    for (int ch = 0; ch < 4; ch++) {
        f16x8 a = *(const f16x8*)(arow + ch * 32);
        #pragma unroll
        for (int nt = 0; nt < 4; nt++) {
            f16x8 b = *(const f16x8*)(wp + (((nt * 4 + ch) * 64 + lane) << 3));
            acc[nt] = __builtin_amdgcn_mfma_f32_16x16x32_f16(a, b, acc[nt], 0, 0, 0);
        }
    }

    float v[4][4];
    #pragma unroll
    for (int nt = 0; nt < 4; nt++) {
        float bias = bo[nt * 16 + m];
        #pragma unroll
        for (int r = 0; r < 4; r++) v[nt][r] = acc[nt][r] + bias;
    }
    #pragma unroll
    for (int r = 0; r < 4; r++) {
        float mx = fmaxf(fmaxf(v[0][r], v[1][r]), fmaxf(v[2][r], v[3][r]));
        #pragma unroll
        for (int off = 1; off < 16; off <<= 1) mx = fmaxf(mx, __shfl_xor(mx, off));
        float s = 0.f;
        #pragma unroll
        for (int nt = 0; nt < 4; nt++) s += __expf(v[nt][r] - mx);
        #pragma unroll
        for (int off = 1; off < 16; off <<= 1) s += __shfl_xor(s, off);
        float lse = mx + logf(s);
        int row = r0 + q * 4 + r;
        #pragma unroll
        for (int nt = 0; nt < 4; nt++)
            out[(size_t)row * NCLS + nt * 16 + m] = v[nt][r] - lse;
    }
}

extern "C" void kernel_launch(void* const* d_in, const int* in_sizes, int n_in,
                              void* d_out, int out_size, void* d_ws, size_t ws_size,
                              hipStream_t stream) {
    const float* x    = (const float*)d_in[0];
    const int*   esrc = (const int*)d_in[1];
    const int*   edst = (const int*)d_in[2];
    const float* ew   = (const float*)d_in[3];
    const float* w_in = (const float*)d_in[4];
    const float* b_in = (const float*)d_in[5];
    const float* gcnw = (const float*)d_in[6];   // [4,128,128]
    const float* wout = (const float*)d_in[7];
    const float* bout = (const float*)d_in[8];
    float* out = (float*)d_out;

    // workspace layout
    unsigned short* h0 = (unsigned short*)d_ws;        // NF ushorts each (fp16)
    unsigned short* hA = h0 + NF;
    unsigned short* hB = hA + NF;
    unsigned short* hi = hB + NF;
    unsigned short* wp = hi + NF;                      // 90112 ushorts packed W (fp16)
    int2* colw = (int2*)(wp + 90112);                  // E int2
    int2* ebuf = colw + N_EDGES;                       // E int2 (bucket-grouped)
    int*  row_ptr       = (int*)(ebuf + N_EDGES);      // N+1
    int*  deg           = row_ptr + (N_NODES + 1);     // N
    int*  blocksum      = deg + N_NODES;               // SCAN_B
    int*  bucket_cnt    = blocksum + SCAN_B;           // NB
    int*  bucket_base   = bucket_cnt + NB;             // NB+1
    int*  bucket_cursor = bucket_base + (NB + 1);      // NB

    const int PART_B = (N_EDGES + CHUNK - 1) / CHUNK;  // 391
    const int MFMA_BLOCKS = (STRIPES + 3) / 4;

    // ---- weight pack ----
    k_prepw<<<(90112 + 255) / 256, 256, 0, stream>>>(gcnw, wout, w_in, wp);

    // ---- bucketed CSR build ----
    hipMemsetAsync(bucket_cnt, 0, NB * sizeof(int), stream);
    k_hist<<<PART_B, 256, 0, stream>>>(edst, bucket_cnt);
    k_scanb<<<1, 512, 0, stream>>>(bucket_cnt, bucket_base, bucket_cursor);
    k_part<<<PART_B, 256, 0, stream>>>(esrc, edst, ew, bucket_cursor, ebuf);
    k_deg<<<NB, 256, 0, stream>>>(ebuf, bucket_base, deg);
    k_scan1<<<SCAN_B, 1024, 0, stream>>>(deg, row_ptr, blocksum);
    k_scan2<<<1, 128, 0, stream>>>(blocksum);
    k_scan3<<<SCAN_B, 1024, 0, stream>>>(row_ptr, blocksum);
    k_scatter2<<<NB, 256, 0, stream>>>(ebuf, bucket_base, row_ptr, colw);

    // h0 = relu(x @ w_in + b_in)
    k_in_mfma<<<MFMA_BLOCKS, 256, 0, stream>>>(x, wp + 73728, b_in, h0);

    const unsigned short* hprev = h0;
    unsigned short* bufs[2] = {hA, hB};
    for (int l = 0; l < 4; l++) {
        float theta = logf(0.5f / (float)(l + 2) + 1.0f);
        k_spmm_csr<<<(N_NODES + 3) / 4, 256, 0, stream>>>(row_ptr, colw, hprev, h0, hi);
        unsigned short* hnew = bufs[l & 1];
        k_layer_mfma<<<MFMA_BLOCKS, 256, 0, stream>>>(hi, hprev, wp + (size_t)l * 16384,
                                                      hnew, theta);
        hprev = hnew;
    }

    // out = log_softmax(h @ w_out + b_out)
    k_out_mfma<<<MFMA_BLOCKS, 256, 0, stream>>>(hprev, wp + 65536, bout, out);
}

// Round 12
// 544.795 us; speedup vs baseline: 1.1818x; 1.0127x over previous
//
#include <hip/hip_runtime.h>
#include <hip/hip_fp16.h>
#include <math.h>

#define N_NODES 100000
#define N_EDGES 1600000
#define DIM     128
#define NCLS    64
#define ALPHA   0.1f

#define NB      391                // ceil(100000/256) dst-buckets of 256 nodes
#define NF      ((size_t)N_NODES * DIM)
#define STRIPES (N_NODES / 16)     // 6250 exact
#define CHUNK   4096               // R8: longer per-bucket runs halve write amp

typedef __attribute__((ext_vector_type(8))) _Float16 f16x8;
typedef __attribute__((ext_vector_type(4))) float    f32x4;

// ---- fp16 pair bitcast helpers ----
__device__ __forceinline__ __half2 u2h2(unsigned int u) {
    union { unsigned int u; __half2 h; } x; x.u = u; return x.h;
}
__device__ __forceinline__ unsigned int h22u(__half2 h) {
    union { unsigned int u; __half2 h; } x; x.h = h; return x.u;
}

// ================= bucketed CSR build =================
// bucket = dst >> 8 (256 nodes/bucket). ebuf entry: x = src | dst_local<<17, y = 0.9*w (f32).

__global__ __launch_bounds__(256) void k_hist(const int* __restrict__ dst,
                                              int* __restrict__ bucket_cnt) {
    __shared__ int hist[NB];
    int t = threadIdx.x;
    for (int b = t; b < NB; b += 256) hist[b] = 0;
    __syncthreads();
    int base = blockIdx.x * CHUNK;
    int end = min(base + CHUNK, N_EDGES);
    for (int i = base + t; i < end; i += 256)
        atomicAdd(&hist[dst[i] >> 8], 1);
    __syncthreads();
    for (int b = t; b < NB; b += 256)
        if (hist[b]) atomicAdd(&bucket_cnt[b], hist[b]);
}

__global__ __launch_bounds__(512) void k_scanb(const int* __restrict__ bucket_cnt,
                                               int* __restrict__ bucket_base,
                                               int* __restrict__ bucket_cursor) {
    __shared__ int s[512];
    int t = threadIdx.x;
    int v = (t < NB) ? bucket_cnt[t] : 0;
    s[t] = v;
    __syncthreads();
    for (int off = 1; off < 512; off <<= 1) {
        int u = (t >= off) ? s[t - off] : 0;
        __syncthreads();
        s[t] += u;
        __syncthreads();
    }
    if (t < NB) {
        int base = s[t] - v;
        bucket_base[t] = base;
        bucket_cursor[t] = base;
    }
    if (t == 0) bucket_base[NB] = N_EDGES;
}

__global__ __launch_bounds__(256) void k_part(const int* __restrict__ src,
                                              const int* __restrict__ dst,
                                              const float* __restrict__ ew,
                                              int* __restrict__ bucket_cursor,
                                              int2* __restrict__ ebuf) {
    __shared__ int lhist[NB], gbase[NB];
    int t = threadIdx.x;
    for (int b = t; b < NB; b += 256) lhist[b] = 0;
    __syncthreads();
    int base = blockIdx.x * CHUNK;
    int end = min(base + CHUNK, N_EDGES);
    for (int i = base + t; i < end; i += 256)
        atomicAdd(&lhist[dst[i] >> 8], 1);
    __syncthreads();
    for (int b = t; b < NB; b += 256) {
        int c = lhist[b];
        gbase[b] = c ? atomicAdd(&bucket_cursor[b], c) : 0;
        lhist[b] = 0;
    }
    __syncthreads();
    for (int i = base + t; i < end; i += 256) {
        int d = dst[i];
        int b = d >> 8;
        int r = atomicAdd(&lhist[b], 1);
        ebuf[gbase[b] + r] = make_int2(src[i] | ((d & 255) << 17),
                                       __float_as_int((1.0f - ALPHA) * ew[i]));
    }
}

// R11: per-bucket counting sort in ONE kernel. Replaces k_deg + scan1/2/3 +
// k_scatter2 (5 dispatches -> 1). row_ptr[node] = bucket_base[b] + LDS prefix;
// pass 2 re-reads the bucket's ebuf (32KB, L2-hot) and scatters to colw.
// colw.y stores the edge weight pre-packed as half2(w,w).
__global__ __launch_bounds__(256) void k_sortbucket(
    const int2* __restrict__ ebuf, const int* __restrict__ bucket_base,
    int* __restrict__ row_ptr, int2* __restrict__ colw) {
    __shared__ int cnt[256], pref[256], lcur[256];
    int t = threadIdx.x, b = blockIdx.x;
    cnt[t] = 0;
    __syncthreads();
    int beg = bucket_base[b], end = bucket_base[b + 1];
    for (int i = beg + t; i < end; i += 256)
        atomicAdd(&cnt[ebuf[i].x >> 17], 1);
    __syncthreads();
    int v = cnt[t];
    pref[t] = v;
    __syncthreads();
    for (int off = 1; off < 256; off <<= 1) {
        int u = (t >= off) ? pref[t - off] : 0;
        __syncthreads();
        pref[t] += u;
        __syncthreads();
    }
    int excl = pref[t] - v;                 // exclusive within-bucket prefix
    int node = b * 256 + t;
    if (node < N_NODES) row_ptr[node] = beg + excl;
    if (b == 0 && t == 0) row_ptr[N_NODES] = N_EDGES;
    lcur[t] = beg + excl;
    __syncthreads();
    for (int i = beg + t; i < end; i += 256) {
        int2 e = ebuf[i];
        int pos = atomicAdd(&lcur[e.x >> 17], 1);
        unsigned int w2 = h22u(__float2half2_rn(__int_as_float(e.y)));
        colw[pos] = make_int2(e.x & 0x1FFFF, (int)w2);
    }
}

// ===== weight pack: fp32 -> fp16 B-fragment order =====
// frag idx = ((nt*4 + ch)*64 + lane)*8 + j ;
// value = W[ch*32 + (lane>>4)*8 + j][nt*16 + (lane&15)]
// layers at wp[l*16384] (l=0..3), w_out at wp[65536] (nt 0..3), w_in at wp[73728].
__global__ void k_prepw(const float* __restrict__ gcnw, const float* __restrict__ wout,
                        const float* __restrict__ win, unsigned short* __restrict__ wp) {
    int tid = blockIdx.x * 256 + threadIdx.x;
    if (tid < 65536) {
        int l = tid >> 14;
        int r = tid & 16383;
        int j = r & 7, lane = (r >> 3) & 63, ch = (r >> 9) & 3, nt = r >> 11;
        int n = nt * 16 + (lane & 15);
        int k = ch * 32 + (lane >> 4) * 8 + j;
        wp[tid] = __half_as_ushort(__float2half(gcnw[l * 16384 + k * 128 + n]));
    } else if (tid < 73728) {
        int r = tid - 65536;
        int j = r & 7, lane = (r >> 3) & 63, ch = (r >> 9) & 3, nt = r >> 11; // nt 0..3
        int n = nt * 16 + (lane & 15);
        int k = ch * 32 + (lane >> 4) * 8 + j;
        wp[tid] = __half_as_ushort(__float2half(wout[k * 64 + n]));
    } else if (tid < 90112) {
        int r = tid - 73728;
        int j = r & 7, lane = (r >> 3) & 63, ch = (r >> 9) & 3, nt = r >> 11; // nt 0..7
        int n = nt * 16 + (lane & 15);
        int k = ch * 32 + (lane >> 4) * 8 + j;
        wp[tid] = __half_as_ushort(__float2half(win[k * 128 + n]));
    }
}

// ===== SpMM gather (fp16 rows): hi[i] = ALPHA*h0[i] + sum_e w*h[src] =====
// 16 lanes/row x 4 edge-slots, uint4 loads, 16-edge predicated pipeline.
// fp16 storage + __hfma2 accumulation; weights pre-packed half2 in colw.y.
// Memory-bound at ~3.7 TB/s L2-miss traffic (R11 counters) — at roofline.
__global__ __launch_bounds__(256, 8) void k_spmm_csr(
    const int* __restrict__ row_ptr, const int2* __restrict__ colw,
    const unsigned short* __restrict__ h, const unsigned short* __restrict__ h0,
    unsigned short* __restrict__ out) {
    int node = blockIdx.x * 4 + (threadIdx.x >> 6);
    if (node >= N_NODES) return;
    int lane = threadIdx.x & 63;
    int slot = lane >> 4;           // edge slot 0..3
    int seg  = lane & 15;           // 16B segment of the row (8 fp16)
    int beg = row_ptr[node], end = row_ptr[node + 1];

    __half2 z2 = __float2half2_rn(0.f);
    __half2 acc2[4] = {z2, z2, z2, z2};
    if (slot == 0) {                // initial residual added once
        uint4 z = *(const uint4*)(h0 + (size_t)node * DIM + seg * 8);
        __half2 al2 = __float2half2_rn(ALPHA);
        acc2[0] = __hmul2(al2, u2h2(z.x));
        acc2[1] = __hmul2(al2, u2h2(z.y));
        acc2[2] = __hmul2(al2, u2h2(z.z));
        acc2[3] = __hmul2(al2, u2h2(z.w));
    }

    int last = end - 1;
    for (int e = beg; e < end; e += 16) {
        int e0 = e + slot, e1 = e0 + 4, e2 = e0 + 8, e3 = e0 + 12;
        int2 c0 = colw[min(e0, last)];
        int2 c1 = colw[min(e1, last)];
        int2 c2 = colw[min(e2, last)];
        int2 c3 = colw[min(e3, last)];
        uint4 r0 = *(const uint4*)(h + (size_t)c0.x * DIM + seg * 8);
        uint4 r1 = *(const uint4*)(h + (size_t)c1.x * DIM + seg * 8);
        uint4 r2 = *(const uint4*)(h + (size_t)c2.x * DIM + seg * 8);
        uint4 r3 = *(const uint4*)(h + (size_t)c3.x * DIM + seg * 8);
        __half2 w0 = (e0 < end) ? u2h2((unsigned int)c0.y) : z2;
        __half2 w1 = (e1 < end) ? u2h2((unsigned int)c1.y) : z2;
        __half2 w2 = (e2 < end) ? u2h2((unsigned int)c2.y) : z2;
        __half2 w3 = (e3 < end) ? u2h2((unsigned int)c3.y) : z2;
        acc2[0] = __hfma2(w0, u2h2(r0.x), acc2[0]);
        acc2[1] = __hfma2(w0, u2h2(r0.y), acc2[1]);
        acc2[2] = __hfma2(w0, u2h2(r0.z), acc2[2]);
        acc2[3] = __hfma2(w0, u2h2(r0.w), acc2[3]);
        acc2[0] = __hfma2(w1, u2h2(r1.x), acc2[0]);
        acc2[1] = __hfma2(w1, u2h2(r1.y), acc2[1]);
        acc2[2] = __hfma2(w1, u2h2(r1.z), acc2[2]);
        acc2[3] = __hfma2(w1, u2h2(r1.w), acc2[3]);
        acc2[0] = __hfma2(w2, u2h2(r2.x), acc2[0]);
        acc2[1] = __hfma2(w2, u2h2(r2.y), acc2[1]);
        acc2[2] = __hfma2(w2, u2h2(r2.z), acc2[2]);
        acc2[3] = __hfma2(w2, u2h2(r2.w), acc2[3]);
        acc2[0] = __hfma2(w3, u2h2(r3.x), acc2[0]);
        acc2[1] = __hfma2(w3, u2h2(r3.y), acc2[1]);
        acc2[2] = __hfma2(w3, u2h2(r3.z), acc2[2]);
        acc2[3] = __hfma2(w3, u2h2(r3.w), acc2[3]);
    }

    // combine the 4 edge-slots (lanes l, l+16, l+32, l+48 hold same dims)
    #pragma unroll
    for (int j = 0; j < 4; j++) {
        unsigned int u = __shfl_xor(h22u(acc2[j]), 16);
        acc2[j] = __hadd2(acc2[j], u2h2(u));
        u = __shfl_xor(h22u(acc2[j]), 32);
        acc2[j] = __hadd2(acc2[j], u2h2(u));
    }

    if (slot == 0) {                           // 16 lanes write 16B each
        *(uint4*)(out + (size_t)node * DIM + seg * 8) =
            make_uint4(h22u(acc2[0]), h22u(acc2[1]), h22u(acc2[2]), h22u(acc2[3]));
    }
}

// ===== MFMA input GEMM: h0 = relu(x @ W_in + b)  (x fp32 -> fp16 in-reg) =====
__global__ __launch_bounds__(256) void k_in_mfma(
    const float* __restrict__ x, const unsigned short* __restrict__ wp,
    const float* __restrict__ b_in, unsigned short* __restrict__ h0) {
    int wave = threadIdx.x >> 6, lane = threadIdx.x & 63;
    int stripe = blockIdx.x * 4 + wave;
    if (stripe >= STRIPES) return;
    int r0 = stripe * 16;
    int m = lane & 15, q = lane >> 4;

    f32x4 acc[8];
    #pragma unroll
    for (int nt = 0; nt < 8; nt++) acc[nt] = (f32x4){0.f, 0.f, 0.f, 0.f};

    const float* xr = x + (size_t)(r0 + m) * DIM + q * 8;
    #pragma unroll
    for (int ch = 0; ch < 4; ch++) {
        float4 a0 = *(const float4*)(xr + ch * 32);
        float4 a1 = *(const float4*)(xr + ch * 32 + 4);
        f16x8 a;
        a[0] = (_Float16)a0.x; a[1] = (_Float16)a0.y;
        a[2] = (_Float16)a0.z; a[3] = (_Float16)a0.w;
        a[4] = (_Float16)a1.x; a[5] = (_Float16)a1.y;
        a[6] = (_Float16)a1.z; a[7] = (_Float16)a1.w;
        #pragma unroll
        for (int nt = 0; nt < 8; nt++) {
            f16x8 b = *(const f16x8*)(wp + (((nt * 4 + ch) * 64 + lane) << 3));
            acc[nt] = __builtin_amdgcn_mfma_f32_16x16x32_f16(a, b, acc[nt], 0, 0, 0);
        }
    }

    #pragma unroll
    for (int nt = 0; nt < 8; nt++) {
        int col = nt * 16 + m;
        float bias = b_in[col];
        #pragma unroll
        for (int r = 0; r < 4; r++) {
            int row = r0 + q * 4 + r;
            h0[(size_t)row * DIM + col] =
                __half_as_ushort(__float2half(fmaxf(acc[nt][r] + bias, 0.f)));
        }
    }
}

// ===== MFMA layer GEMM: h = relu(theta*(s@W) + (1-theta)*s + hprev) =====
__global__ __launch_bounds__(256) void k_layer_mfma(
    const unsigned short* __restrict__ s_in, const unsigned short* __restrict__ hprev,
    const unsigned short* __restrict__ wp, unsigned short* __restrict__ hout,
    float theta) {
    int wave = threadIdx.x >> 6, lane = threadIdx.x & 63;
    int stripe = blockIdx.x * 4 + wave;
    if (stripe >= STRIPES) return;
    int r0 = stripe * 16;
    int m = lane & 15, q = lane >> 4;
    float omt = 1.f - theta;

    f32x4 acc[8];
    #pragma unroll
    for (int nt = 0; nt < 8; nt++) acc[nt] = (f32x4){0.f, 0.f, 0.f, 0.f};

    const unsigned short* arow = s_in + (size_t)(r0 + m) * DIM + q * 8;
    #pragma unroll
    for (int ch = 0; ch < 4; ch++) {
        f16x8 a = *(const f16x8*)(arow + ch * 32);
        #pragma unroll
        for (int nt = 0; nt < 8; nt++) {
            f16x8 b = *(const f16x8*)(wp + (((nt * 4 + ch) * 64 + lane) << 3));
            acc[nt] = __builtin_amdgcn_mfma_f32_16x16x32_f16(a, b, acc[nt], 0, 0, 0);
        }
    }

    #pragma unroll
    for (int nt = 0; nt < 8; nt++) {
        int col = nt * 16 + m;
        #pragma unroll
        for (int r = 0; r < 4; r++) {
            int row = r0 + q * 4 + r;
            size_t idx = (size_t)row * DIM + col;
            float sup = __half2float(__ushort_as_half(s_in[idx]));
            float hp  = __half2float(__ushort_as_half(hprev[idx]));
            float o = theta * acc[nt][r] + omt * sup + hp;
            hout[idx] = __half_as_ushort(__float2half(fmaxf(o, 0.f)));
        }
    }
}

// ===== MFMA output GEMM + log_softmax =====
__global__ __launch_bounds__(256) void k_out_mfma(
    const unsigned short* __restrict__ h, const unsigned short* __restrict__ wp,
    const float* __restrict__ bo, float* __restrict__ out) {
    int wave = threadIdx.x >> 6, lane = threadIdx.x & 63;
    int stripe = blockIdx.x * 4 + wave;
    if (stripe >= STRIPES) return;
    int r0 = stripe * 16;
    int m = lane & 15, q = lane >> 4;

    f32x4 acc[4];
    #pragma unroll
    for (int nt = 0; nt < 4; nt++) acc[nt] = (f32x4){0.f, 0.f, 0.f, 0.f};

    const unsigned short* arow = h + (size_t)(r0 + m) * DIM + q * 8;
    #pragma unroll
    for (int ch = 0; ch < 4; ch++) {
        f16x8 a = *(const f16x8*)(arow + ch * 32);
        #pragma unroll
        for (int nt = 0; nt < 4; nt++) {
            f16x8 b = *(const f16x8*)(wp + (((nt * 4 + ch) * 64 + lane) << 3));
            acc[nt] = __builtin_amdgcn_mfma_f32_16x16x32_f16(a, b, acc[nt], 0, 0, 0);
        }
    }

    float v[4][4];
    #pragma unroll
    for (int nt = 0; nt < 4; nt++) {
        float bias = bo[nt * 16 + m];
        #pragma unroll
        for (int r = 0; r < 4; r++) v[nt][r] = acc[nt][r] + bias;
    }
    #pragma unroll
    for (int r = 0; r < 4; r++) {
        float mx = fmaxf(fmaxf(v[0][r], v[1][r]), fmaxf(v[2][r], v[3][r]));
        #pragma unroll
        for (int off = 1; off < 16; off <<= 1) mx = fmaxf(mx, __shfl_xor(mx, off));
        float s = 0.f;
        #pragma unroll
        for (int nt = 0; nt < 4; nt++) s += __expf(v[nt][r] - mx);
        #pragma unroll
        for (int off = 1; off < 16; off <<= 1) s += __shfl_xor(s, off);
        float lse = mx + logf(s);
        int row = r0 + q * 4 + r;
        #pragma unroll
        for (int nt = 0; nt < 4; nt++)
            out[(size_t)row * NCLS + nt * 16 + m] = v[nt][r] - lse;
    }
}

extern "C" void kernel_launch(void* const* d_in, const int* in_sizes, int n_in,
                              void* d_out, int out_size, void* d_ws, size_t ws_size,
                              hipStream_t stream) {
    const float* x    = (const float*)d_in[0];
    const int*   esrc = (const int*)d_in[1];
    const int*   edst = (const int*)d_in[2];
    const float* ew   = (const float*)d_in[3];
    const float* w_in = (const float*)d_in[4];
    const float* b_in = (const float*)d_in[5];
    const float* gcnw = (const float*)d_in[6];   // [4,128,128]
    const float* wout = (const float*)d_in[7];
    const float* bout = (const float*)d_in[8];
    float* out = (float*)d_out;

    // workspace layout
    unsigned short* h0 = (unsigned short*)d_ws;        // NF ushorts each (fp16)
    unsigned short* hA = h0 + NF;
    unsigned short* hB = hA + NF;
    unsigned short* hi = hB + NF;
    unsigned short* wp = hi + NF;                      // 90112 ushorts packed W (fp16)
    int2* colw = (int2*)(wp + 90112);                  // E int2
    int2* ebuf = colw + N_EDGES;                       // E int2 (bucket-grouped)
    int*  row_ptr       = (int*)(ebuf + N_EDGES);      // N+1
    int*  bucket_cnt    = row_ptr + (N_NODES + 1);     // NB
    int*  bucket_base   = bucket_cnt + NB;             // NB+1
    int*  bucket_cursor = bucket_base + (NB + 1);      // NB

    const int PART_B = (N_EDGES + CHUNK - 1) / CHUNK;  // 391
    const int MFMA_BLOCKS = (STRIPES + 3) / 4;

    // ---- weight pack ----
    k_prepw<<<(90112 + 255) / 256, 256, 0, stream>>>(gcnw, wout, w_in, wp);

    // ---- bucketed CSR build (4 kernels; R11: sortbucket replaces 5-kernel tail) ----
    hipMemsetAsync(bucket_cnt, 0, NB * sizeof(int), stream);
    k_hist<<<PART_B, 256, 0, stream>>>(edst, bucket_cnt);
    k_scanb<<<1, 512, 0, stream>>>(bucket_cnt, bucket_base, bucket_cursor);
    k_part<<<PART_B, 256, 0, stream>>>(esrc, edst, ew, bucket_cursor, ebuf);
    k_sortbucket<<<NB, 256, 0, stream>>>(ebuf, bucket_base, row_ptr, colw);

    // h0 = relu(x @ w_in + b_in)
    k_in_mfma<<<MFMA_BLOCKS, 256, 0, stream>>>(x, wp + 73728, b_in, h0);

    const unsigned short* hprev = h0;
    unsigned short* bufs[2] = {hA, hB};
    for (int l = 0; l < 4; l++) {
        float theta = logf(0.5f / (float)(l + 2) + 1.0f);
        k_spmm_csr<<<(N_NODES + 3) / 4, 256, 0, stream>>>(row_ptr, colw, hprev, h0, hi);
        unsigned short* hnew = bufs[l & 1];
        k_layer_mfma<<<MFMA_BLOCKS, 256, 0, stream>>>(hi, hprev, wp + (size_t)l * 16384,
                                                      hnew, theta);
        hprev = hnew;
    }

    // out = log_softmax(h @ w_out + b_out)
    k_out_mfma<<<MFMA_BLOCKS, 256, 0, stream>>>(hprev, wp + 65536, bout, out);
}

// Round 13
// 486.951 us; speedup vs baseline: 1.3222x; 1.1188x over previous
//
#include <hip/hip_runtime.h>
#include <hip/hip_fp16.h>
#include <math.h>

#define N_NODES 100000
#define N_EDGES 1600000
#define DIM     128
#define NCLS    64
#define ALPHA   0.1f

#define NB      391                // ceil(100000/256) dst-buckets of 256 nodes
#define NF      ((size_t)N_NODES * DIM)
#define STRIPES (N_NODES / 16)     // 6250 exact (no tail!)
#define CHUNK   4096               // R8: longer per-bucket runs halve write amp

typedef __attribute__((ext_vector_type(8))) _Float16 f16x8;
typedef __attribute__((ext_vector_type(4))) float    f32x4;

// ---- fp16 pair bitcast helpers ----
__device__ __forceinline__ __half2 u2h2(unsigned int u) {
    union { unsigned int u; __half2 h; } x; x.u = u; return x.h;
}
__device__ __forceinline__ unsigned int h22u(__half2 h) {
    union { unsigned int u; __half2 h; } x; x.h = h; return x.u;
}

// ================= bucketed CSR build =================
// bucket = dst >> 8 (256 nodes/bucket). ebuf entry: x = src | dst_local<<17, y = 0.9*w (f32).

__global__ __launch_bounds__(256) void k_hist(const int* __restrict__ dst,
                                              int* __restrict__ bucket_cnt) {
    __shared__ int hist[NB];
    int t = threadIdx.x;
    for (int b = t; b < NB; b += 256) hist[b] = 0;
    __syncthreads();
    int base = blockIdx.x * CHUNK;
    int end = min(base + CHUNK, N_EDGES);
    for (int i = base + t; i < end; i += 256)
        atomicAdd(&hist[dst[i] >> 8], 1);
    __syncthreads();
    for (int b = t; b < NB; b += 256)
        if (hist[b]) atomicAdd(&bucket_cnt[b], hist[b]);
}

__global__ __launch_bounds__(512) void k_scanb(const int* __restrict__ bucket_cnt,
                                               int* __restrict__ bucket_base,
                                               int* __restrict__ bucket_cursor) {
    __shared__ int s[512];
    int t = threadIdx.x;
    int v = (t < NB) ? bucket_cnt[t] : 0;
    s[t] = v;
    __syncthreads();
    for (int off = 1; off < 512; off <<= 1) {
        int u = (t >= off) ? s[t - off] : 0;
        __syncthreads();
        s[t] += u;
        __syncthreads();
    }
    if (t < NB) {
        int base = s[t] - v;
        bucket_base[t] = base;
        bucket_cursor[t] = base;
    }
    if (t == 0) bucket_base[NB] = N_EDGES;
}

__global__ __launch_bounds__(256) void k_part(const int* __restrict__ src,
                                              const int* __restrict__ dst,
                                              const float* __restrict__ ew,
                                              int* __restrict__ bucket_cursor,
                                              int2* __restrict__ ebuf) {
    __shared__ int lhist[NB], gbase[NB];
    int t = threadIdx.x;
    for (int b = t; b < NB; b += 256) lhist[b] = 0;
    __syncthreads();
    int base = blockIdx.x * CHUNK;
    int end = min(base + CHUNK, N_EDGES);
    for (int i = base + t; i < end; i += 256)
        atomicAdd(&lhist[dst[i] >> 8], 1);
    __syncthreads();
    for (int b = t; b < NB; b += 256) {
        int c = lhist[b];
        gbase[b] = c ? atomicAdd(&bucket_cursor[b], c) : 0;
        lhist[b] = 0;
    }
    __syncthreads();
    for (int i = base + t; i < end; i += 256) {
        int d = dst[i];
        int b = d >> 8;
        int r = atomicAdd(&lhist[b], 1);
        ebuf[gbase[b] + r] = make_int2(src[i] | ((d & 255) << 17),
                                       __float_as_int((1.0f - ALPHA) * ew[i]));
    }
}

// R11: per-bucket counting sort in ONE kernel (replaced k_deg+scan1/2/3+scatter2).
// row_ptr[node] = bucket_base[b] + LDS prefix; pass 2 re-reads the bucket's ebuf
// (32KB, L2-hot) and scatters to colw. colw.y = edge weight pre-packed half2(w,w).
__global__ __launch_bounds__(256) void k_sortbucket(
    const int2* __restrict__ ebuf, const int* __restrict__ bucket_base,
    int* __restrict__ row_ptr, int2* __restrict__ colw) {
    __shared__ int cnt[256], pref[256], lcur[256];
    int t = threadIdx.x, b = blockIdx.x;
    cnt[t] = 0;
    __syncthreads();
    int beg = bucket_base[b], end = bucket_base[b + 1];
    for (int i = beg + t; i < end; i += 256)
        atomicAdd(&cnt[ebuf[i].x >> 17], 1);
    __syncthreads();
    int v = cnt[t];
    pref[t] = v;
    __syncthreads();
    for (int off = 1; off < 256; off <<= 1) {
        int u = (t >= off) ? pref[t - off] : 0;
        __syncthreads();
        pref[t] += u;
        __syncthreads();
    }
    int excl = pref[t] - v;                 // exclusive within-bucket prefix
    int node = b * 256 + t;
    if (node < N_NODES) row_ptr[node] = beg + excl;
    if (b == 0 && t == 0) row_ptr[N_NODES] = N_EDGES;
    lcur[t] = beg + excl;
    __syncthreads();
    for (int i = beg + t; i < end; i += 256) {
        int2 e = ebuf[i];
        int pos = atomicAdd(&lcur[e.x >> 17], 1);
        unsigned int w2 = h22u(__float2half2_rn(__int_as_float(e.y)));
        colw[pos] = make_int2(e.x & 0x1FFFF, (int)w2);
    }
}

// ===== weight pack: fp32 -> fp16 B-fragment order =====
// R12: layer weights are identity-folded: W'_l = theta_l*W_l + (1-theta_l)*I,
// so the layer is out = sup @ W' + hprev (no separate (1-theta)*sup term).
// frag idx = ((nt*4 + ch)*64 + lane)*8 + j ;
// value = W[ch*32 + (lane>>4)*8 + j][nt*16 + (lane&15)]
// layers at wp[l*16384] (l=0..3), w_out at wp[65536] (nt 0..3), w_in at wp[73728].
__global__ void k_prepw(const float* __restrict__ gcnw, const float* __restrict__ wout,
                        const float* __restrict__ win, unsigned short* __restrict__ wp) {
    int tid = blockIdx.x * 256 + threadIdx.x;
    if (tid < 65536) {
        int l = tid >> 14;
        int r = tid & 16383;
        int j = r & 7, lane = (r >> 3) & 63, ch = (r >> 9) & 3, nt = r >> 11;
        int n = nt * 16 + (lane & 15);
        int k = ch * 32 + (lane >> 4) * 8 + j;
        float theta = logf(0.5f / (float)(l + 2) + 1.0f);
        float v = theta * gcnw[l * 16384 + k * 128 + n] + ((k == n) ? (1.f - theta) : 0.f);
        wp[tid] = __half_as_ushort(__float2half(v));
    } else if (tid < 73728) {
        int r = tid - 65536;
        int j = r & 7, lane = (r >> 3) & 63, ch = (r >> 9) & 3, nt = r >> 11; // nt 0..3
        int n = nt * 16 + (lane & 15);
        int k = ch * 32 + (lane >> 4) * 8 + j;
        wp[tid] = __half_as_ushort(__float2half(wout[k * 64 + n]));
    } else if (tid < 90112) {
        int r = tid - 73728;
        int j = r & 7, lane = (r >> 3) & 63, ch = (r >> 9) & 3, nt = r >> 11; // nt 0..7
        int n = nt * 16 + (lane & 15);
        int k = ch * 32 + (lane >> 4) * 8 + j;
        wp[tid] = __half_as_ushort(__float2half(win[k * 128 + n]));
    }
}

// ===== R12 FUSED layer: SpMM(16 nodes -> LDS) + MFMA(sup@W' + hprev) =====
// Phase 1 keeps the proven SpMM wave shape: each of 4 waves gathers 4 nodes
// (16 lanes/row x 4 edge-slots, uint4 loads, 16-edge pipeline) — same per-wave
// loads-in-flight as the standalone 60.8us kernel (unlike R0's failed fusion).
// LDS tile [16][128] fp16 with 16B-granule XOR swizzle g^row:
//   write: 2-way bank alias (free); read: b128 structural minimum.
// Phase 2: 4 waves x 2 nt-tiles of 16x16x32 f16 MFMA; epilogue += hprev, relu.
__global__ __launch_bounds__(256, 6) void k_layer_fused(
    const int* __restrict__ row_ptr, const int2* __restrict__ colw,
    const unsigned short* __restrict__ h,      // hprev: gather source + residual
    const unsigned short* __restrict__ h0,
    const unsigned short* __restrict__ wp,     // folded W' fragments
    unsigned short* __restrict__ hout) {
    __shared__ unsigned short sup[16 * 128];   // 4KB
    int wave = threadIdx.x >> 6, lane = threadIdx.x & 63;
    int slot = lane >> 4;           // edge slot 0..3
    int seg  = lane & 15;           // 16B granule of the row (8 fp16)
    int r0 = blockIdx.x * 16;       // STRIPES*16 == N_NODES exactly, no tail

    __half2 z2 = __float2half2_rn(0.f);
    __half2 al2 = __float2half2_rn(ALPHA);

    // ---- phase 1: gather 4 nodes per wave into swizzled LDS ----
    for (int i = 0; i < 4; i++) {
        int n_loc = wave * 4 + i;
        int node = r0 + n_loc;
        int beg = row_ptr[node], end = row_ptr[node + 1];

        __half2 acc2[4] = {z2, z2, z2, z2};
        if (slot == 0) {            // initial residual added once
            uint4 z = *(const uint4*)(h0 + (size_t)node * DIM + seg * 8);
            acc2[0] = __hmul2(al2, u2h2(z.x));
            acc2[1] = __hmul2(al2, u2h2(z.y));
            acc2[2] = __hmul2(al2, u2h2(z.z));
            acc2[3] = __hmul2(al2, u2h2(z.w));
        }

        int last = end - 1;
        for (int e = beg; e < end; e += 16) {
            int e0 = e + slot, e1 = e0 + 4, e2 = e0 + 8, e3 = e0 + 12;
            int2 c0 = colw[min(e0, last)];
            int2 c1 = colw[min(e1, last)];
            int2 c2 = colw[min(e2, last)];
            int2 c3 = colw[min(e3, last)];
            uint4 r0v = *(const uint4*)(h + (size_t)c0.x * DIM + seg * 8);
            uint4 r1v = *(const uint4*)(h + (size_t)c1.x * DIM + seg * 8);
            uint4 r2v = *(const uint4*)(h + (size_t)c2.x * DIM + seg * 8);
            uint4 r3v = *(const uint4*)(h + (size_t)c3.x * DIM + seg * 8);
            __half2 w0 = (e0 < end) ? u2h2((unsigned int)c0.y) : z2;
            __half2 w1 = (e1 < end) ? u2h2((unsigned int)c1.y) : z2;
            __half2 w2 = (e2 < end) ? u2h2((unsigned int)c2.y) : z2;
            __half2 w3 = (e3 < end) ? u2h2((unsigned int)c3.y) : z2;
            acc2[0] = __hfma2(w0, u2h2(r0v.x), acc2[0]);
            acc2[1] = __hfma2(w0, u2h2(r0v.y), acc2[1]);
            acc2[2] = __hfma2(w0, u2h2(r0v.z), acc2[2]);
            acc2[3] = __hfma2(w0, u2h2(r0v.w), acc2[3]);
            acc2[0] = __hfma2(w1, u2h2(r1v.x), acc2[0]);
            acc2[1] = __hfma2(w1, u2h2(r1v.y), acc2[1]);
            acc2[2] = __hfma2(w1, u2h2(r1v.z), acc2[2]);
            acc2[3] = __hfma2(w1, u2h2(r1v.w), acc2[3]);
            acc2[0] = __hfma2(w2, u2h2(r2v.x), acc2[0]);
            acc2[1] = __hfma2(w2, u2h2(r2v.y), acc2[1]);
            acc2[2] = __hfma2(w2, u2h2(r2v.z), acc2[2]);
            acc2[3] = __hfma2(w2, u2h2(r2v.w), acc2[3]);
            acc2[0] = __hfma2(w3, u2h2(r3v.x), acc2[0]);
            acc2[1] = __hfma2(w3, u2h2(r3v.y), acc2[1]);
            acc2[2] = __hfma2(w3, u2h2(r3v.z), acc2[2]);
            acc2[3] = __hfma2(w3, u2h2(r3v.w), acc2[3]);
        }

        #pragma unroll
        for (int j = 0; j < 4; j++) {
            unsigned int u = __shfl_xor(h22u(acc2[j]), 16);
            acc2[j] = __hadd2(acc2[j], u2h2(u));
            u = __shfl_xor(h22u(acc2[j]), 32);
            acc2[j] = __hadd2(acc2[j], u2h2(u));
        }

        if (slot == 0) {            // swizzled granule write: g = seg ^ n_loc
            int g = seg ^ n_loc;
            *(uint4*)(sup + n_loc * 128 + g * 8) =
                make_uint4(h22u(acc2[0]), h22u(acc2[1]), h22u(acc2[2]), h22u(acc2[3]));
        }
    }
    __syncthreads();                // uniform: all 256 threads

    // ---- phase 2: 16x128 @ W'(128x128), wave computes nt = wave*2 + {0,1} ----
    int m = lane & 15, q = lane >> 4;
    f32x4 acc[2];
    acc[0] = (f32x4){0.f, 0.f, 0.f, 0.f};
    acc[1] = (f32x4){0.f, 0.f, 0.f, 0.f};
    #pragma unroll
    for (int ch = 0; ch < 4; ch++) {
        int g = (4 * ch + q) ^ m;   // read-side swizzle matches writer
        f16x8 a = *(const f16x8*)(sup + m * 128 + g * 8);
        #pragma unroll
        for (int t2 = 0; t2 < 2; t2++) {
            int nt = wave * 2 + t2;
            f16x8 b = *(const f16x8*)(wp + (((nt * 4 + ch) * 64 + lane) << 3));
            acc[t2] = __builtin_amdgcn_mfma_f32_16x16x32_f16(a, b, acc[t2], 0, 0, 0);
        }
    }
    #pragma unroll
    for (int t2 = 0; t2 < 2; t2++) {
        int col = (wave * 2 + t2) * 16 + m;
        #pragma unroll
        for (int r = 0; r < 4; r++) {
            int row = r0 + q * 4 + r;
            size_t idx = (size_t)row * DIM + col;
            float hp = __half2float(__ushort_as_half(h[idx]));
            float o = acc[t2][r] + hp;
            hout[idx] = __half_as_ushort(__float2half(fmaxf(o, 0.f)));
        }
    }
}

// ===== MFMA input GEMM: h0 = relu(x @ W_in + b)  (x fp32 -> fp16 in-reg) =====
__global__ __launch_bounds__(256) void k_in_mfma(
    const float* __restrict__ x, const unsigned short* __restrict__ wp,
    const float* __restrict__ b_in, unsigned short* __restrict__ h0) {
    int wave = threadIdx.x >> 6, lane = threadIdx.x & 63;
    int stripe = blockIdx.x * 4 + wave;
    if (stripe >= STRIPES) return;
    int r0 = stripe * 16;
    int m = lane & 15, q = lane >> 4;

    f32x4 acc[8];
    #pragma unroll
    for (int nt = 0; nt < 8; nt++) acc[nt] = (f32x4){0.f, 0.f, 0.f, 0.f};

    const float* xr = x + (size_t)(r0 + m) * DIM + q * 8;
    #pragma unroll
    for (int ch = 0; ch < 4; ch++) {
        float4 a0 = *(const float4*)(xr + ch * 32);
        float4 a1 = *(const float4*)(xr + ch * 32 + 4);
        f16x8 a;
        a[0] = (_Float16)a0.x; a[1] = (_Float16)a0.y;
        a[2] = (_Float16)a0.z; a[3] = (_Float16)a0.w;
        a[4] = (_Float16)a1.x; a[5] = (_Float16)a1.y;
        a[6] = (_Float16)a1.z; a[7] = (_Float16)a1.w;
        #pragma unroll
        for (int nt = 0; nt < 8; nt++) {
            f16x8 b = *(const f16x8*)(wp + (((nt * 4 + ch) * 64 + lane) << 3));
            acc[nt] = __builtin_amdgcn_mfma_f32_16x16x32_f16(a, b, acc[nt], 0, 0, 0);
        }
    }

    #pragma unroll
    for (int nt = 0; nt < 8; nt++) {
        int col = nt * 16 + m;
        float bias = b_in[col];
        #pragma unroll
        for (int r = 0; r < 4; r++) {
            int row = r0 + q * 4 + r;
            h0[(size_t)row * DIM + col] =
                __half_as_ushort(__float2half(fmaxf(acc[nt][r] + bias, 0.f)));
        }
    }
}

// ===== MFMA output GEMM + log_softmax =====
__global__ __launch_bounds__(256) void k_out_mfma(
    const unsigned short* __restrict__ h, const unsigned short* __restrict__ wp,
    const float* __restrict__ bo, float* __restrict__ out) {
    int wave = threadIdx.x >> 6, lane = threadIdx.x & 63;
    int stripe = blockIdx.x * 4 + wave;
    if (stripe >= STRIPES) return;
    int r0 = stripe * 16;
    int m = lane & 15, q = lane >> 4;

    f32x4 acc[4];
    #pragma unroll
    for (int nt = 0; nt < 4; nt++) acc[nt] = (f32x4){0.f, 0.f, 0.f, 0.f};

    const unsigned short* arow = h + (size_t)(r0 + m) * DIM + q * 8;
    #pragma unroll
    for (int ch = 0; ch < 4; ch++) {
        f16x8 a = *(const f16x8*)(arow + ch * 32);
        #pragma unroll
        for (int nt = 0; nt < 4; nt++) {
            f16x8 b = *(const f16x8*)(wp + (((nt * 4 + ch) * 64 + lane) << 3));
            acc[nt] = __builtin_amdgcn_mfma_f32_16x16x32_f16(a, b, acc[nt], 0, 0, 0);
        }
    }

    float v[4][4];
    #pragma unroll
    for (int nt = 0; nt < 4; nt++) {
        float bias = bo[nt * 16 + m];
        #pragma unroll
        for (int r = 0; r < 4; r++) v[nt][r] = acc[nt][r] + bias;
    }
    #pragma unroll
    for (int r = 0; r < 4; r++) {
        float mx = fmaxf(fmaxf(v[0][r], v[1][r]), fmaxf(v[2][r], v[3][r]));
        #pragma unroll
        for (int off = 1; off < 16; off <<= 1) mx = fmaxf(mx, __shfl_xor(mx, off));
        float s = 0.f;
        #pragma unroll
        for (int nt = 0; nt < 4; nt++) s += __expf(v[nt][r] - mx);
        #pragma unroll
        for (int off = 1; off < 16; off <<= 1) s += __shfl_xor(s, off);
        float lse = mx + logf(s);
        int row = r0 + q * 4 + r;
        #pragma unroll
        for (int nt = 0; nt < 4; nt++)
            out[(size_t)row * NCLS + nt * 16 + m] = v[nt][r] - lse;
    }
}

extern "C" void kernel_launch(void* const* d_in, const int* in_sizes, int n_in,
                              void* d_out, int out_size, void* d_ws, size_t ws_size,
                              hipStream_t stream) {
    const float* x    = (const float*)d_in[0];
    const int*   esrc = (const int*)d_in[1];
    const int*   edst = (const int*)d_in[2];
    const float* ew   = (const float*)d_in[3];
    const float* w_in = (const float*)d_in[4];
    const float* b_in = (const float*)d_in[5];
    const float* gcnw = (const float*)d_in[6];   // [4,128,128]
    const float* wout = (const float*)d_in[7];
    const float* bout = (const float*)d_in[8];
    float* out = (float*)d_out;

    // workspace layout (hi slot removed — fused path)
    unsigned short* h0 = (unsigned short*)d_ws;        // NF ushorts each (fp16)
    unsigned short* hA = h0 + NF;
    unsigned short* hB = hA + NF;
    unsigned short* wp = hB + NF;                      // 90112 ushorts packed W (fp16)
    int2* colw = (int2*)(wp + 90112);                  // E int2
    int2* ebuf = colw + N_EDGES;                       // E int2 (bucket-grouped)
    int*  row_ptr       = (int*)(ebuf + N_EDGES);      // N+1
    int*  bucket_cnt    = row_ptr + (N_NODES + 1);     // NB
    int*  bucket_base   = bucket_cnt + NB;             // NB+1
    int*  bucket_cursor = bucket_base + (NB + 1);      // NB

    const int PART_B = (N_EDGES + CHUNK - 1) / CHUNK;  // 391
    const int MFMA_BLOCKS = (STRIPES + 3) / 4;         // 1563

    // ---- weight pack (layer weights identity-folded) ----
    k_prepw<<<(90112 + 255) / 256, 256, 0, stream>>>(gcnw, wout, w_in, wp);

    // ---- bucketed CSR build ----
    hipMemsetAsync(bucket_cnt, 0, NB * sizeof(int), stream);
    k_hist<<<PART_B, 256, 0, stream>>>(edst, bucket_cnt);
    k_scanb<<<1, 512, 0, stream>>>(bucket_cnt, bucket_base, bucket_cursor);
    k_part<<<PART_B, 256, 0, stream>>>(esrc, edst, ew, bucket_cursor, ebuf);
    k_sortbucket<<<NB, 256, 0, stream>>>(ebuf, bucket_base, row_ptr, colw);

    // h0 = relu(x @ w_in + b_in)
    k_in_mfma<<<MFMA_BLOCKS, 256, 0, stream>>>(x, wp + 73728, b_in, h0);

    const unsigned short* hprev = h0;
    unsigned short* bufs[2] = {hA, hB};
    for (int l = 0; l < 4; l++) {
        unsigned short* hnew = bufs[l & 1];
        k_layer_fused<<<STRIPES, 256, 0, stream>>>(row_ptr, colw, hprev, h0,
                                                   wp + (size_t)l * 16384, hnew);
        hprev = hnew;
    }

    // out = log_softmax(h @ w_out + b_out)
    k_out_mfma<<<MFMA_BLOCKS, 256, 0, stream>>>(hprev, wp + 65536, bout, out);
}

// Round 14
// 464.347 us; speedup vs baseline: 1.3866x; 1.0487x over previous
//
#include <hip/hip_runtime.h>
#include <hip/hip_fp16.h>
#include <math.h>

#define N_NODES 100000
#define N_EDGES 1600000
#define DIM     128
#define NCLS    64
#define ALPHA   0.1f

#define NB      391                // ceil(100000/256) dst-buckets of 256 nodes
#define CAP     5120               // R13: fixed bucket capacity (mean 4096, 16-sigma margin)
#define NF      ((size_t)N_NODES * DIM)
#define STRIPES (N_NODES / 16)     // 6250 exact (no tail!)
#define CHUNK   4096               // R8: longer per-bucket runs halve write amp

typedef __attribute__((ext_vector_type(8))) _Float16 f16x8;
typedef __attribute__((ext_vector_type(4))) float    f32x4;

// ---- fp16 pair bitcast helpers ----
__device__ __forceinline__ __half2 u2h2(unsigned int u) {
    union { unsigned int u; __half2 h; } x; x.u = u; return x.h;
}
__device__ __forceinline__ unsigned int h22u(__half2 h) {
    union { unsigned int u; __half2 h; } x; x.h = h; return x.u;
}

// ================= bucketed CSR build (R13: fixed-capacity, no hist/scan) ===
// bucket = dst >> 8 (256 nodes/bucket). Bucket b owns ebuf/colw slots
// [b*CAP, b*CAP+cnt_b). ebuf entry: x = src | dst_local<<17, y = 0.9*w (f32).

__global__ __launch_bounds__(256) void k_part(const int* __restrict__ src,
                                              const int* __restrict__ dst,
                                              const float* __restrict__ ew,
                                              int* __restrict__ bucket_cursor,
                                              int2* __restrict__ ebuf) {
    __shared__ int lhist[NB], gbase[NB];
    int t = threadIdx.x;
    for (int b = t; b < NB; b += 256) lhist[b] = 0;
    __syncthreads();
    int base = blockIdx.x * CHUNK;
    int end = min(base + CHUNK, N_EDGES);
    for (int i = base + t; i < end; i += 256)
        atomicAdd(&lhist[dst[i] >> 8], 1);
    __syncthreads();
    for (int b = t; b < NB; b += 256) {
        int c = lhist[b];
        gbase[b] = c ? atomicAdd(&bucket_cursor[b], c) : 0;
        lhist[b] = 0;
    }
    __syncthreads();
    for (int i = base + t; i < end; i += 256) {
        int d = dst[i];
        int b = d >> 8;
        int r = atomicAdd(&lhist[b], 1);
        ebuf[(size_t)b * CAP + gbase[b] + r] =
            make_int2(src[i] | ((d & 255) << 17),
                      __float_as_int((1.0f - ALPHA) * ew[i]));
    }
}

// Per-bucket counting sort. rowspan[node] = {beg, end} into the bucket's
// fixed colw slot (no global contiguity needed). colw.y = half2(w,w).
__global__ __launch_bounds__(256) void k_sortbucket(
    const int2* __restrict__ ebuf, const int* __restrict__ bucket_cursor,
    int2* __restrict__ rowspan, int2* __restrict__ colw) {
    __shared__ int cnt[256], pref[256], lcur[256];
    int t = threadIdx.x, b = blockIdx.x;
    cnt[t] = 0;
    __syncthreads();
    int beg = b * CAP, end = beg + bucket_cursor[b];
    for (int i = beg + t; i < end; i += 256)
        atomicAdd(&cnt[ebuf[i].x >> 17], 1);
    __syncthreads();
    int v = cnt[t];
    pref[t] = v;
    __syncthreads();
    for (int off = 1; off < 256; off <<= 1) {
        int u = (t >= off) ? pref[t - off] : 0;
        __syncthreads();
        pref[t] += u;
        __syncthreads();
    }
    int excl = pref[t] - v;                 // exclusive within-bucket prefix
    int node = b * 256 + t;
    if (node < N_NODES) rowspan[node] = make_int2(beg + excl, beg + excl + v);
    lcur[t] = beg + excl;
    __syncthreads();
    for (int i = beg + t; i < end; i += 256) {
        int2 e = ebuf[i];
        int pos = atomicAdd(&lcur[e.x >> 17], 1);
        unsigned int w2 = h22u(__float2half2_rn(__int_as_float(e.y)));
        colw[pos] = make_int2(e.x & 0x1FFFF, (int)w2);
    }
}

// ===== weight pack: fp32 -> fp16 B-fragment order =====
// R12: layer weights identity-folded: W'_l = theta_l*W_l + (1-theta_l)*I.
// frag idx = ((nt*4 + ch)*64 + lane)*8 + j ;
// value = W[ch*32 + (lane>>4)*8 + j][nt*16 + (lane&15)]
// layers at wp[l*16384] (l=0..3), w_out at wp[65536] (nt 0..3), w_in at wp[73728].
__global__ void k_prepw(const float* __restrict__ gcnw, const float* __restrict__ wout,
                        const float* __restrict__ win, unsigned short* __restrict__ wp) {
    int tid = blockIdx.x * 256 + threadIdx.x;
    if (tid < 65536) {
        int l = tid >> 14;
        int r = tid & 16383;
        int j = r & 7, lane = (r >> 3) & 63, ch = (r >> 9) & 3, nt = r >> 11;
        int n = nt * 16 + (lane & 15);
        int k = ch * 32 + (lane >> 4) * 8 + j;
        float theta = logf(0.5f / (float)(l + 2) + 1.0f);
        float v = theta * gcnw[l * 16384 + k * 128 + n] + ((k == n) ? (1.f - theta) : 0.f);
        wp[tid] = __half_as_ushort(__float2half(v));
    } else if (tid < 73728) {
        int r = tid - 65536;
        int j = r & 7, lane = (r >> 3) & 63, ch = (r >> 9) & 3, nt = r >> 11; // nt 0..3
        int n = nt * 16 + (lane & 15);
        int k = ch * 32 + (lane >> 4) * 8 + j;
        wp[tid] = __half_as_ushort(__float2half(wout[k * 64 + n]));
    } else if (tid < 90112) {
        int r = tid - 73728;
        int j = r & 7, lane = (r >> 3) & 63, ch = (r >> 9) & 3, nt = r >> 11; // nt 0..7
        int n = nt * 16 + (lane & 15);
        int k = ch * 32 + (lane >> 4) * 8 + j;
        wp[tid] = __half_as_ushort(__float2half(win[k * 128 + n]));
    }
}

// ---- shared phase-1 gather: 4 nodes/wave into swizzled LDS tile ----
__device__ __forceinline__ void gather_tile(
    const int2* __restrict__ rowspan, const int2* __restrict__ colw,
    const unsigned short* __restrict__ h, const unsigned short* __restrict__ h0,
    unsigned short* sup, int r0, int wave, int slot, int seg) {
    __half2 z2 = __float2half2_rn(0.f);
    __half2 al2 = __float2half2_rn(ALPHA);
    for (int i = 0; i < 4; i++) {
        int n_loc = wave * 4 + i;
        int node = r0 + n_loc;
        int2 span = rowspan[node];
        int beg = span.x, end = span.y;

        __half2 acc2[4] = {z2, z2, z2, z2};
        if (slot == 0) {            // initial residual added once
            uint4 z = *(const uint4*)(h0 + (size_t)node * DIM + seg * 8);
            acc2[0] = __hmul2(al2, u2h2(z.x));
            acc2[1] = __hmul2(al2, u2h2(z.y));
            acc2[2] = __hmul2(al2, u2h2(z.z));
            acc2[3] = __hmul2(al2, u2h2(z.w));
        }

        int last = end - 1;
        for (int e = beg; e < end; e += 16) {
            int e0 = e + slot, e1 = e0 + 4, e2 = e0 + 8, e3 = e0 + 12;
            int2 c0 = colw[min(e0, last)];
            int2 c1 = colw[min(e1, last)];
            int2 c2 = colw[min(e2, last)];
            int2 c3 = colw[min(e3, last)];
            uint4 r0v = *(const uint4*)(h + (size_t)c0.x * DIM + seg * 8);
            uint4 r1v = *(const uint4*)(h + (size_t)c1.x * DIM + seg * 8);
            uint4 r2v = *(const uint4*)(h + (size_t)c2.x * DIM + seg * 8);
            uint4 r3v = *(const uint4*)(h + (size_t)c3.x * DIM + seg * 8);
            __half2 w0 = (e0 < end) ? u2h2((unsigned int)c0.y) : z2;
            __half2 w1 = (e1 < end) ? u2h2((unsigned int)c1.y) : z2;
            __half2 w2 = (e2 < end) ? u2h2((unsigned int)c2.y) : z2;
            __half2 w3 = (e3 < end) ? u2h2((unsigned int)c3.y) : z2;
            acc2[0] = __hfma2(w0, u2h2(r0v.x), acc2[0]);
            acc2[1] = __hfma2(w0, u2h2(r0v.y), acc2[1]);
            acc2[2] = __hfma2(w0, u2h2(r0v.z), acc2[2]);
            acc2[3] = __hfma2(w0, u2h2(r0v.w), acc2[3]);
            acc2[0] = __hfma2(w1, u2h2(r1v.x), acc2[0]);
            acc2[1] = __hfma2(w1, u2h2(r1v.y), acc2[1]);
            acc2[2] = __hfma2(w1, u2h2(r1v.z), acc2[2]);
            acc2[3] = __hfma2(w1, u2h2(r1v.w), acc2[3]);
            acc2[0] = __hfma2(w2, u2h2(r2v.x), acc2[0]);
            acc2[1] = __hfma2(w2, u2h2(r2v.y), acc2[1]);
            acc2[2] = __hfma2(w2, u2h2(r2v.z), acc2[2]);
            acc2[3] = __hfma2(w2, u2h2(r2v.w), acc2[3]);
            acc2[0] = __hfma2(w3, u2h2(r3v.x), acc2[0]);
            acc2[1] = __hfma2(w3, u2h2(r3v.y), acc2[1]);
            acc2[2] = __hfma2(w3, u2h2(r3v.z), acc2[2]);
            acc2[3] = __hfma2(w3, u2h2(r3v.w), acc2[3]);
        }

        #pragma unroll
        for (int j = 0; j < 4; j++) {
            unsigned int u = __shfl_xor(h22u(acc2[j]), 16);
            acc2[j] = __hadd2(acc2[j], u2h2(u));
            u = __shfl_xor(h22u(acc2[j]), 32);
            acc2[j] = __hadd2(acc2[j], u2h2(u));
        }

        if (slot == 0) {            // swizzled granule write: g = seg ^ n_loc
            int g = seg ^ n_loc;
            *(uint4*)(sup + n_loc * 128 + g * 8) =
                make_uint4(h22u(acc2[0]), h22u(acc2[1]), h22u(acc2[2]), h22u(acc2[3]));
        }
    }
}

// ===== FUSED layer: SpMM(16 nodes -> LDS) + MFMA(sup@W' + hprev) =====
__global__ __launch_bounds__(256, 6) void k_layer_fused(
    const int2* __restrict__ rowspan, const int2* __restrict__ colw,
    const unsigned short* __restrict__ h,      // hprev: gather source + residual
    const unsigned short* __restrict__ h0,
    const unsigned short* __restrict__ wp,     // folded W' fragments
    unsigned short* __restrict__ hout) {
    __shared__ unsigned short sup[16 * 128];   // 4KB
    int wave = threadIdx.x >> 6, lane = threadIdx.x & 63;
    int slot = lane >> 4, seg = lane & 15;
    int r0 = blockIdx.x * 16;

    gather_tile(rowspan, colw, h, h0, sup, r0, wave, slot, seg);
    __syncthreads();

    int m = lane & 15, q = lane >> 4;
    f32x4 acc[2];
    acc[0] = (f32x4){0.f, 0.f, 0.f, 0.f};
    acc[1] = (f32x4){0.f, 0.f, 0.f, 0.f};
    #pragma unroll
    for (int ch = 0; ch < 4; ch++) {
        int g = (4 * ch + q) ^ m;
        f16x8 a = *(const f16x8*)(sup + m * 128 + g * 8);
        #pragma unroll
        for (int t2 = 0; t2 < 2; t2++) {
            int nt = wave * 2 + t2;
            f16x8 b = *(const f16x8*)(wp + (((nt * 4 + ch) * 64 + lane) << 3));
            acc[t2] = __builtin_amdgcn_mfma_f32_16x16x32_f16(a, b, acc[t2], 0, 0, 0);
        }
    }
    #pragma unroll
    for (int t2 = 0; t2 < 2; t2++) {
        int col = (wave * 2 + t2) * 16 + m;
        #pragma unroll
        for (int r = 0; r < 4; r++) {
            int row = r0 + q * 4 + r;
            size_t idx = (size_t)row * DIM + col;
            float hp = __half2float(__ushort_as_half(h[idx]));
            float o = acc[t2][r] + hp;
            hout[idx] = __half_as_ushort(__float2half(fmaxf(o, 0.f)));
        }
    }
}

// ===== R13 FUSED LAST layer: + out-GEMM + log_softmax (no h_final round-trip) =====
__global__ __launch_bounds__(256, 6) void k_layer_fused_out(
    const int2* __restrict__ rowspan, const int2* __restrict__ colw,
    const unsigned short* __restrict__ h, const unsigned short* __restrict__ h0,
    const unsigned short* __restrict__ wp,     // folded W' (layer 3)
    const unsigned short* __restrict__ wpo,    // w_out fragments
    const float* __restrict__ bo, float* __restrict__ out) {
    __shared__ unsigned short sup[16 * 128];   // 4KB
    __shared__ unsigned short hfin[16 * 128];  // 4KB final-h tile
    int wave = threadIdx.x >> 6, lane = threadIdx.x & 63;
    int slot = lane >> 4, seg = lane & 15;
    int r0 = blockIdx.x * 16;

    gather_tile(rowspan, colw, h, h0, sup, r0, wave, slot, seg);
    __syncthreads();

    int m = lane & 15, q = lane >> 4;
    f32x4 acc[2];
    acc[0] = (f32x4){0.f, 0.f, 0.f, 0.f};
    acc[1] = (f32x4){0.f, 0.f, 0.f, 0.f};
    #pragma unroll
    for (int ch = 0; ch < 4; ch++) {
        int g = (4 * ch + q) ^ m;
        f16x8 a = *(const f16x8*)(sup + m * 128 + g * 8);
        #pragma unroll
        for (int t2 = 0; t2 < 2; t2++) {
            int nt = wave * 2 + t2;
            f16x8 b = *(const f16x8*)(wp + (((nt * 4 + ch) * 64 + lane) << 3));
            acc[t2] = __builtin_amdgcn_mfma_f32_16x16x32_f16(a, b, acc[t2], 0, 0, 0);
        }
    }
    // stage relu(o) into hfin (swizzled scalar writes; 2-way bank alias = free)
    #pragma unroll
    for (int t2 = 0; t2 < 2; t2++) {
        int col = (wave * 2 + t2) * 16 + m;
        #pragma unroll
        for (int r = 0; r < 4; r++) {
            int row = q * 4 + r;
            size_t idx = (size_t)(r0 + row) * DIM + col;
            float hp = __half2float(__ushort_as_half(h[idx]));
            float o = fmaxf(acc[t2][r] + hp, 0.f);
            hfin[row * 128 + ((col >> 3) ^ row) * 8 + (col & 7)] =
                __half_as_ushort(__float2half(o));
        }
    }
    __syncthreads();

    // wave 0: 16x128 @ w_out(128x64) + bias + row log_softmax
    if (wave == 0) {
        f32x4 acc4[4];
        #pragma unroll
        for (int nt = 0; nt < 4; nt++) acc4[nt] = (f32x4){0.f, 0.f, 0.f, 0.f};
        #pragma unroll
        for (int ch = 0; ch < 4; ch++) {
            int g = (4 * ch + q) ^ m;
            f16x8 a = *(const f16x8*)(hfin + m * 128 + g * 8);
            #pragma unroll
            for (int nt = 0; nt < 4; nt++) {
                f16x8 b = *(const f16x8*)(wpo + (((nt * 4 + ch) * 64 + lane) << 3));
                acc4[nt] = __builtin_amdgcn_mfma_f32_16x16x32_f16(a, b, acc4[nt], 0, 0, 0);
            }
        }
        float v[4][4];
        #pragma unroll
        for (int nt = 0; nt < 4; nt++) {
            float bias = bo[nt * 16 + m];
            #pragma unroll
            for (int r = 0; r < 4; r++) v[nt][r] = acc4[nt][r] + bias;
        }
        #pragma unroll
        for (int r = 0; r < 4; r++) {
            float mx = fmaxf(fmaxf(v[0][r], v[1][r]), fmaxf(v[2][r], v[3][r]));
            #pragma unroll
            for (int off = 1; off < 16; off <<= 1) mx = fmaxf(mx, __shfl_xor(mx, off));
            float s = 0.f;
            #pragma unroll
            for (int nt = 0; nt < 4; nt++) s += __expf(v[nt][r] - mx);
            #pragma unroll
            for (int off = 1; off < 16; off <<= 1) s += __shfl_xor(s, off);
            float lse = mx + logf(s);
            int row = r0 + q * 4 + r;
            #pragma unroll
            for (int nt = 0; nt < 4; nt++)
                out[(size_t)row * NCLS + nt * 16 + m] = v[nt][r] - lse;
        }
    }
}

// ===== MFMA input GEMM: h0 = relu(x @ W_in + b)  (x fp32 -> fp16 in-reg) =====
__global__ __launch_bounds__(256) void k_in_mfma(
    const float* __restrict__ x, const unsigned short* __restrict__ wp,
    const float* __restrict__ b_in, unsigned short* __restrict__ h0) {
    int wave = threadIdx.x >> 6, lane = threadIdx.x & 63;
    int stripe = blockIdx.x * 4 + wave;
    if (stripe >= STRIPES) return;
    int r0 = stripe * 16;
    int m = lane & 15, q = lane >> 4;

    f32x4 acc[8];
    #pragma unroll
    for (int nt = 0; nt < 8; nt++) acc[nt] = (f32x4){0.f, 0.f, 0.f, 0.f};

    const float* xr = x + (size_t)(r0 + m) * DIM + q * 8;
    #pragma unroll
    for (int ch = 0; ch < 4; ch++) {
        float4 a0 = *(const float4*)(xr + ch * 32);
        float4 a1 = *(const float4*)(xr + ch * 32 + 4);
        f16x8 a;
        a[0] = (_Float16)a0.x; a[1] = (_Float16)a0.y;
        a[2] = (_Float16)a0.z; a[3] = (_Float16)a0.w;
        a[4] = (_Float16)a1.x; a[5] = (_Float16)a1.y;
        a[6] = (_Float16)a1.z; a[7] = (_Float16)a1.w;
        #pragma unroll
        for (int nt = 0; nt < 8; nt++) {
            f16x8 b = *(const f16x8*)(wp + (((nt * 4 + ch) * 64 + lane) << 3));
            acc[nt] = __builtin_amdgcn_mfma_f32_16x16x32_f16(a, b, acc[nt], 0, 0, 0);
        }
    }

    #pragma unroll
    for (int nt = 0; nt < 8; nt++) {
        int col = nt * 16 + m;
        float bias = b_in[col];
        #pragma unroll
        for (int r = 0; r < 4; r++) {
            int row = r0 + q * 4 + r;
            h0[(size_t)row * DIM + col] =
                __half_as_ushort(__float2half(fmaxf(acc[nt][r] + bias, 0.f)));
        }
    }
}

extern "C" void kernel_launch(void* const* d_in, const int* in_sizes, int n_in,
                              void* d_out, int out_size, void* d_ws, size_t ws_size,
                              hipStream_t stream) {
    const float* x    = (const float*)d_in[0];
    const int*   esrc = (const int*)d_in[1];
    const int*   edst = (const int*)d_in[2];
    const float* ew   = (const float*)d_in[3];
    const float* w_in = (const float*)d_in[4];
    const float* b_in = (const float*)d_in[5];
    const float* gcnw = (const float*)d_in[6];   // [4,128,128]
    const float* wout = (const float*)d_in[7];
    const float* bout = (const float*)d_in[8];
    float* out = (float*)d_out;

    // workspace layout
    unsigned short* h0 = (unsigned short*)d_ws;        // NF ushorts each (fp16)
    unsigned short* hA = h0 + NF;
    unsigned short* hB = hA + NF;
    unsigned short* wp = hB + NF;                      // 90112 ushorts packed W (fp16)
    int2* colw = (int2*)(wp + 90112);                  // NB*CAP int2 (fixed slots)
    int2* ebuf = colw + (size_t)NB * CAP;              // NB*CAP int2
    int2* rowspan = ebuf + (size_t)NB * CAP;           // N int2 {beg,end}
    int*  bucket_cursor = (int*)(rowspan + N_NODES);   // NB

    const int PART_B = (N_EDGES + CHUNK - 1) / CHUNK;  // 391
    const int MFMA_BLOCKS = (STRIPES + 3) / 4;         // 1563

    // ---- weight pack (layer weights identity-folded) ----
    k_prepw<<<(90112 + 255) / 256, 256, 0, stream>>>(gcnw, wout, w_in, wp);

    // ---- CSR build: 2 kernels (R13: fixed-capacity buckets, no hist/scan) ----
    hipMemsetAsync(bucket_cursor, 0, NB * sizeof(int), stream);
    k_part<<<PART_B, 256, 0, stream>>>(esrc, edst, ew, bucket_cursor, ebuf);
    k_sortbucket<<<NB, 256, 0, stream>>>(ebuf, bucket_cursor, rowspan, colw);

    // h0 = relu(x @ w_in + b_in)
    k_in_mfma<<<MFMA_BLOCKS, 256, 0, stream>>>(x, wp + 73728, b_in, h0);

    const unsigned short* hprev = h0;
    unsigned short* bufs[2] = {hA, hB};
    for (int l = 0; l < 3; l++) {
        unsigned short* hnew = bufs[l & 1];
        k_layer_fused<<<STRIPES, 256, 0, stream>>>(rowspan, colw, hprev, h0,
                                                   wp + (size_t)l * 16384, hnew);
        hprev = hnew;
    }
    // last layer fused with out-GEMM + log_softmax
    k_layer_fused_out<<<STRIPES, 256, 0, stream>>>(rowspan, colw, hprev, h0,
                                                   wp + 3 * 16384, wp + 65536,
                                                   bout, out);
}